// Round 3
// baseline (698.656 us; speedup 1.0000x reference)
//
#include <hip/hip_runtime.h>
#include <hip/hip_bf16.h>

#define HQn 16
#define HKVn 4
#define HDn 64
#define Bn 2
#define Sn 1024
#define Hn 1024
#define En 8
#define In 2048
#define Tn 2048
#define EPSf 1e-6f

typedef __attribute__((ext_vector_type(8))) short bf16x8;
typedef __attribute__((ext_vector_type(4))) float f32x4;

// ---------------- helpers ----------------
__device__ __forceinline__ unsigned short f2bf(float f) {
  unsigned u = __float_as_uint(f);
  u += 0x7fffu + ((u >> 16) & 1u);
  return (unsigned short)(u >> 16);
}
__device__ __forceinline__ float bf2f(unsigned short u) {
  return __uint_as_float(((unsigned)u) << 16);
}
__device__ __forceinline__ void gll16(const void* g, void* l) {
  __builtin_amdgcn_global_load_lds(
      (const __attribute__((address_space(1))) void*)g,
      (__attribute__((address_space(3))) void*)l, 16, 0, 0);
}

// ---------------- transpose + f32->bf16: src[Z][R][C] -> dst[Z][C][R] ----------------
__global__ __launch_bounds__(256) void k_tcvt(
    const float* __restrict__ src, unsigned short* __restrict__ dst,
    int R, int C, size_t sZ, size_t dZ) {
  src += (size_t)blockIdx.z * sZ;
  dst += (size_t)blockIdx.z * dZ;
  int c0 = blockIdx.x * 64, r0 = blockIdx.y * 64;
  __shared__ float t[64][65];
  int tid = threadIdx.x;
  int lr = tid >> 4, lc = (tid & 15) * 4;
#pragma unroll
  for (int p = 0; p < 4; p++) {
    float4 v = *(const float4*)(src + (size_t)(r0 + lr + p * 16) * C + c0 + lc);
    t[lr + p * 16][lc + 0] = v.x; t[lr + p * 16][lc + 1] = v.y;
    t[lr + p * 16][lc + 2] = v.z; t[lr + p * 16][lc + 3] = v.w;
  }
  __syncthreads();
  int oc = tid >> 2;
  int seg = (tid & 3) * 16;
  unsigned pk[8];
#pragma unroll
  for (int j = 0; j < 8; j++) {
    unsigned short lo = f2bf(t[seg + 2 * j][oc]);
    unsigned short hi = f2bf(t[seg + 2 * j + 1][oc]);
    pk[j] = (unsigned)lo | ((unsigned)hi << 16);
  }
  uint4* dp = (uint4*)(dst + (size_t)(c0 + oc) * R + r0 + seg);
  dp[0] = make_uint4(pk[0], pk[1], pk[2], pk[3]);
  dp[1] = make_uint4(pk[4], pk[5], pk[6], pk[7]);
}

// ---------------- transpose + f32 -> (hi,lo) bf16: src[R][C] -> dsth/dstl[C][R] ------
__global__ __launch_bounds__(256) void k_tcvt2(
    const float* __restrict__ src, unsigned short* __restrict__ dsth,
    unsigned short* __restrict__ dstl, int R, int C) {
  int c0 = blockIdx.x * 64, r0 = blockIdx.y * 64;
  __shared__ float t[64][65];
  int tid = threadIdx.x;
  int lr = tid >> 4, lc = (tid & 15) * 4;
#pragma unroll
  for (int p = 0; p < 4; p++) {
    float4 v = *(const float4*)(src + (size_t)(r0 + lr + p * 16) * C + c0 + lc);
    t[lr + p * 16][lc + 0] = v.x; t[lr + p * 16][lc + 1] = v.y;
    t[lr + p * 16][lc + 2] = v.z; t[lr + p * 16][lc + 3] = v.w;
  }
  __syncthreads();
  int oc = tid >> 2;
  int seg = (tid & 3) * 16;
  unsigned pkh[8], pkl[8];
#pragma unroll
  for (int j = 0; j < 8; j++) {
    float a = t[seg + 2 * j][oc], b = t[seg + 2 * j + 1][oc];
    unsigned short ahh = f2bf(a), bhh = f2bf(b);
    unsigned short alo = f2bf(a - bf2f(ahh)), blo = f2bf(b - bf2f(bhh));
    pkh[j] = (unsigned)ahh | ((unsigned)bhh << 16);
    pkl[j] = (unsigned)alo | ((unsigned)blo << 16);
  }
  size_t db = (size_t)(c0 + oc) * R + r0 + seg;
  uint4* dph = (uint4*)(dsth + db);
  dph[0] = make_uint4(pkh[0], pkh[1], pkh[2], pkh[3]);
  dph[1] = make_uint4(pkh[4], pkh[5], pkh[6], pkh[7]);
  uint4* dpl = (uint4*)(dstl + db);
  dpl[0] = make_uint4(pkl[0], pkl[1], pkl[2], pkl[3]);
  dpl[1] = make_uint4(pkl[4], pkl[5], pkl[6], pkl[7]);
}

// ---------------- RMSNorm over H=1024, one block per row -> hi/lo bf16 ----------------
__global__ __launch_bounds__(256) void k_rmsnorm(
    const float* __restrict__ x, const float* __restrict__ w,
    unsigned short* __restrict__ outh, unsigned short* __restrict__ outl) {
  int row = blockIdx.x, tid = threadIdx.x;
  size_t off = (size_t)row * Hn + tid * 4;
  float4 v = *(const float4*)(x + off);
  float ss = v.x * v.x + v.y * v.y + v.z * v.z + v.w * v.w;
#pragma unroll
  for (int o = 32; o > 0; o >>= 1) ss += __shfl_xor(ss, o);
  __shared__ float ls[4];
  if ((tid & 63) == 0) ls[tid >> 6] = ss;
  __syncthreads();
  float tot = ls[0] + ls[1] + ls[2] + ls[3];
  float sc = rsqrtf(tot * (1.0f / Hn) + EPSf);
  float4 wv = *(const float4*)(w + tid * 4);
  float o0 = v.x * sc * wv.x, o1 = v.y * sc * wv.y;
  float o2 = v.z * sc * wv.z, o3 = v.w * sc * wv.w;
  ushort4 h4, l4;
  h4.x = f2bf(o0); l4.x = f2bf(o0 - bf2f(h4.x));
  h4.y = f2bf(o1); l4.y = f2bf(o1 - bf2f(h4.y));
  h4.z = f2bf(o2); l4.z = f2bf(o2 - bf2f(h4.z));
  h4.w = f2bf(o3); l4.w = f2bf(o3 - bf2f(h4.w));
  *(ushort4*)(outh + off) = h4;
  *(ushort4*)(outl + off) = l4;
}

// ---------------- residual add + RMSNorm (f32 outs + bf16 copy of t) ----------------
__global__ __launch_bounds__(256) void k_resid_norm(
    const float* __restrict__ x, const float* __restrict__ y,
    const float* __restrict__ w, float* __restrict__ x2out,
    float* __restrict__ tout, unsigned short* __restrict__ tbf) {
  int row = blockIdx.x, tid = threadIdx.x;
  size_t off = (size_t)row * Hn + tid * 4;
  float4 xv = *(const float4*)(x + off);
  float4 yv = *(const float4*)(y + off);
  float4 s;
  s.x = xv.x + yv.x; s.y = xv.y + yv.y; s.z = xv.z + yv.z; s.w = xv.w + yv.w;
  *(float4*)(x2out + off) = s;
  float ss = s.x * s.x + s.y * s.y + s.z * s.z + s.w * s.w;
#pragma unroll
  for (int o = 32; o > 0; o >>= 1) ss += __shfl_xor(ss, o);
  __shared__ float ls[4];
  if ((tid & 63) == 0) ls[tid >> 6] = ss;
  __syncthreads();
  float tot = ls[0] + ls[1] + ls[2] + ls[3];
  float sc = rsqrtf(tot * (1.0f / Hn) + EPSf);
  float4 wv4 = *(const float4*)(w + tid * 4);
  float4 t4;
  t4.x = s.x * sc * wv4.x; t4.y = s.y * sc * wv4.y;
  t4.z = s.z * sc * wv4.z; t4.w = s.w * sc * wv4.w;
  *(float4*)(tout + off) = t4;
  ushort4 b4;
  b4.x = f2bf(t4.x); b4.y = f2bf(t4.y); b4.z = f2bf(t4.z); b4.w = f2bf(t4.w);
  *(ushort4*)(tbf + off) = b4;
}

// ---------------- split-precision MFMA GEMM: C(MxN f32) = A @ B^T -------------------
// A hi/lo bf16 [M][K]; B hi/lo bf16 [N][K]. 64x128 tile, BK=32, 4 waves 2x2.
// STATIC double buffer (separate named LDS arrays, 2x-unrolled K loop) so the
// compiler can prove the prefetch gll16 writes don't alias the ds_reads and
// keep the loads in flight during the MFMA phase.
__global__ __launch_bounds__(256) void k_pgemm(
    const unsigned short* __restrict__ Ah, const unsigned short* __restrict__ Al,
    const unsigned short* __restrict__ Bth, const unsigned short* __restrict__ Btl,
    float* __restrict__ C, int N, int K) {
  __shared__ __align__(16) short sAh0[2048], sAh1[2048], sAl0[2048], sAl1[2048];
  __shared__ __align__(16) short sBh0[4096], sBh1[4096], sBl0[4096], sBl1[4096];
  int tid = threadIdx.x, wave = tid >> 6, lane = tid & 63;
  int n0 = blockIdx.x * 128, m0 = blockIdx.y * 64;
  int wm = wave >> 1, wn = wave & 1;
  int r0 = ((tid >> 6) << 4) | (tid & 15);
  int k0 = ((tid >> 4) & 3) * 8;
  int r1 = r0 + 64;
  const unsigned short* pAh = Ah + (size_t)(m0 + r0) * K + k0;
  const unsigned short* pAl = Al + (size_t)(m0 + r0) * K + k0;
  const unsigned short* pBh0 = Bth + (size_t)(n0 + r0) * K + k0;
  const unsigned short* pBl0 = Btl + (size_t)(n0 + r0) * K + k0;
  const unsigned short* pBh1 = Bth + (size_t)(n0 + r1) * K + k0;
  const unsigned short* pBl1 = Btl + (size_t)(n0 + r1) * K + k0;
  size_t d0 = (size_t)tid * 8, d1 = (size_t)(256 + tid) * 8;
#define PG_STAGE(S, kb) do { \
    gll16(pAh + (kb), sAh##S + d0); \
    gll16(pAl + (kb), sAl##S + d0); \
    gll16(pBh0 + (kb), sBh##S + d0); \
    gll16(pBl0 + (kb), sBl##S + d0); \
    gll16(pBh1 + (kb), sBh##S + d1); \
    gll16(pBl1 + (kb), sBl##S + d1); \
  } while (0)
#define PG_COMP(S) do { \
    bf16x8 ah[2], al[2], bh[4], bl[4]; \
    _Pragma("unroll") \
    for (int i = 0; i < 2; i++) { \
      ah[i] = *(const bf16x8*)(sAh##S + ((wm * 2 + i) * 64 + lane) * 8); \
      al[i] = *(const bf16x8*)(sAl##S + ((wm * 2 + i) * 64 + lane) * 8); \
    } \
    _Pragma("unroll") \
    for (int j = 0; j < 4; j++) { \
      bh[j] = *(const bf16x8*)(sBh##S + ((wn * 4 + j) * 64 + lane) * 8); \
      bl[j] = *(const bf16x8*)(sBl##S + ((wn * 4 + j) * 64 + lane) * 8); \
    } \
    _Pragma("unroll") \
    for (int i = 0; i < 2; i++) \
      _Pragma("unroll") \
      for (int j = 0; j < 4; j++) { \
        acc[i][j] = __builtin_amdgcn_mfma_f32_16x16x32_bf16(ah[i], bh[j], acc[i][j], 0, 0, 0); \
        acc[i][j] = __builtin_amdgcn_mfma_f32_16x16x32_bf16(ah[i], bl[j], acc[i][j], 0, 0, 0); \
        acc[i][j] = __builtin_amdgcn_mfma_f32_16x16x32_bf16(al[i], bh[j], acc[i][j], 0, 0, 0); \
      } \
  } while (0)
  f32x4 zf = {0.f, 0.f, 0.f, 0.f};
  f32x4 acc[2][4];
#pragma unroll
  for (int i = 0; i < 2; i++)
#pragma unroll
    for (int j = 0; j < 4; j++) acc[i][j] = zf;
  PG_STAGE(0, 0);
  __syncthreads();
  for (int kb = 0; kb < K; kb += 64) {
    PG_STAGE(1, kb + 32);
    PG_COMP(0);
    __syncthreads();
    if (kb + 64 < K) PG_STAGE(0, kb + 64);
    PG_COMP(1);
    __syncthreads();
  }
#undef PG_STAGE
#undef PG_COMP
  int cr = (lane >> 4) * 4, cc = lane & 15;
#pragma unroll
  for (int i = 0; i < 2; i++) {
    int row0 = m0 + (wm * 2 + i) * 16 + cr;
#pragma unroll
    for (int j = 0; j < 4; j++) {
      int col = n0 + (wn * 4 + j) * 16 + cc;
#pragma unroll
      for (int r = 0; r < 4; r++)
        C[(size_t)(row0 + r) * N + col] = acc[i][j][r];
    }
  }
}

// ---------------- q/k head-RMSNorm + RoPE; emits q_t f32, K/V split-bf16 swizzled ----
// input qkv: [token][1536] = [q 0..1023 | k 1024..1279 | v 1280..1535]
__global__ __launch_bounds__(256) void k_qkv_post(
    const float* __restrict__ qkv, const float* __restrict__ qn_w,
    const float* __restrict__ kn_w, const float* __restrict__ freq,
    float* __restrict__ q_t,
    unsigned short* __restrict__ kT8h, unsigned short* __restrict__ kT8l,
    unsigned short* __restrict__ vT8h, unsigned short* __restrict__ vT8l,
    float* __restrict__ k_out, float* __restrict__ v_out) {
  int gw = blockIdx.x * 4 + (threadIdx.x >> 6);
  int lane = threadIdx.x & 63;
  int token = gw / 24;
  int hh = gw % 24;
  int b = token / Sn, s = token % Sn;
  if (hh >= 20) {  // v head
    int h = hh - 20;
    float v = qkv[(size_t)token * 1536 + 1280 + h * HDn + lane];
    unsigned short hi = f2bf(v);
    unsigned short lo = f2bf(v - bf2f(hi));
    size_t vb = (((size_t)(b * HKVn + h) * 128 + (s >> 3)) * 64 + lane) * 8 + (s & 7);
    vT8h[vb] = hi; vT8l[vb] = lo;
    v_out[(size_t)token * (HKVn * HDn) + h * HDn + lane] = v;
    return;
  }
  bool isq = hh < 16;
  int h = isq ? hh : hh - 16;
  float val = isq ? qkv[(size_t)token * 1536 + h * HDn + lane]
                  : qkv[(size_t)token * 1536 + 1024 + h * HDn + lane];
  float ss = val * val;
#pragma unroll
  for (int o = 32; o > 0; o >>= 1) ss += __shfl_xor(ss, o);
  float scn = rsqrtf(ss * (1.0f / HDn) + EPSf);
  float w = isq ? qn_w[lane] : kn_w[lane];
  float xn = val * scn * w;
  float f = freq[(size_t)s * (HDn / 2) + (lane & 31)];
  float c = cosf(f), sn = sinf(f);
  float partner = __shfl_xor(xn, 32);
  float out = (lane < 32) ? (xn * c - partner * sn) : (partner * sn + xn * c);
  if (isq) {
    q_t[(((size_t)(b * HQn + h)) * Sn + s) * HDn + lane] = out;
  } else {
    unsigned short hi = f2bf(out);
    unsigned short lo = f2bf(out - bf2f(hi));
    size_t kb = (((size_t)(b * HKVn + h) * 8 + (lane >> 3)) * Sn + s) * 8 + (lane & 7);
    kT8h[kb] = hi; kT8l[kb] = lo;
    k_out[(size_t)token * (HKVn * HDn) + h * HDn + lane] = out;
  }
}

// ---------------- MFMA flash attention, split-precision (hi/lo bf16 = ~f32 exact) ----
__global__ __launch_bounds__(256) void k_attn_mfma(
    const float* __restrict__ q_t,
    const unsigned short* __restrict__ kT8h, const unsigned short* __restrict__ kT8l,
    const unsigned short* __restrict__ vT8h, const unsigned short* __restrict__ vT8l,
    unsigned short* __restrict__ yh, unsigned short* __restrict__ yl) {
  __shared__ __align__(16) unsigned short klh[4096], kll[4096];  // [do][key][din]
  __shared__ __align__(16) unsigned short vth[4096], vtl[4096];  // [ko][d][kin]
  __shared__ __align__(16) unsigned short Ph[4][1152], Pl[4][1152];  // [w][row][72]
  int bid = blockIdx.x;
  int qt = 63 - (bid & 63);       // long blocks first
  int kvh = (bid >> 6) & 3;
  int b = bid >> 8;
  int tid = threadIdx.x, w = tid >> 6, lane = tid & 63;
  int h = kvh * 4 + w;
  int g = lane >> 4, li = lane & 15;
  const float* qrow = q_t + (((size_t)(b * HQn + h) * Sn) + qt * 16 + li) * HDn + g * 8;
  bf16x8 qh[2], ql[2];
#pragma unroll
  for (int kc = 0; kc < 2; kc++) {
    float v[8];
    *(float4*)(v) = *(const float4*)(qrow + kc * 32);
    *(float4*)(v + 4) = *(const float4*)(qrow + kc * 32 + 4);
#pragma unroll
    for (int j = 0; j < 8; j++) {
      unsigned short hi = f2bf(v[j]);
      qh[kc][j] = (short)hi;
      ql[kc][j] = (short)f2bf(v[j] - bf2f(hi));
    }
  }
  size_t bh = (size_t)(b * HKVn + kvh) * 65536;
  f32x4 acc[4];
  f32x4 zf = {0.f, 0.f, 0.f, 0.f};
#pragma unroll
  for (int nt = 0; nt < 4; nt++) acc[nt] = zf;
  float m_[4] = {-1e30f, -1e30f, -1e30f, -1e30f};
  float l_[4] = {0.f, 0.f, 0.f, 0.f};
  int rowb = qt * 16 + g * 4;
  int kmax = qt * 16 + 15;
  for (int kk = 0; kk <= kmax; kk += 64) {
    __syncthreads();
#pragma unroll
    for (int i = 0; i < 2; i++) {
      int idx = w * 2 + i;
      gll16(kT8h + bh + (size_t)idx * 8192 + (size_t)kk * 8 + lane * 8, &klh[idx * 512]);
      gll16(kT8l + bh + (size_t)idx * 8192 + (size_t)kk * 8 + lane * 8, &kll[idx * 512]);
      gll16(vT8h + bh + (size_t)(kk / 8 + idx) * 512 + lane * 8, &vth[idx * 512]);
      gll16(vT8l + bh + (size_t)(kk / 8 + idx) * 512 + lane * 8, &vtl[idx * 512]);
    }
    __syncthreads();
    // ---- scores: 4 key-tiles of 16 ----
    f32x4 st[4];
#pragma unroll
    for (int kt = 0; kt < 4; kt++) st[kt] = zf;
#pragma unroll
    for (int kt = 0; kt < 4; kt++)
#pragma unroll
      for (int kc = 0; kc < 2; kc++) {
        int ko = (kc * 4 + g) * 512 + (kt * 16 + li) * 8;
        bf16x8 kh = *(const bf16x8*)&klh[ko];
        bf16x8 klo = *(const bf16x8*)&kll[ko];
        st[kt] = __builtin_amdgcn_mfma_f32_16x16x32_bf16(qh[kc], kh, st[kt], 0, 0, 0);
        st[kt] = __builtin_amdgcn_mfma_f32_16x16x32_bf16(qh[kc], klo, st[kt], 0, 0, 0);
        st[kt] = __builtin_amdgcn_mfma_f32_16x16x32_bf16(ql[kc], kh, st[kt], 0, 0, 0);
      }
    // ---- online softmax (rows rowb..rowb+3 per lane) ----
    float mx[4] = {-1e30f, -1e30f, -1e30f, -1e30f};
#pragma unroll
    for (int kt = 0; kt < 4; kt++) {
      int key = kk + kt * 16 + li;
#pragma unroll
      for (int r = 0; r < 4; r++) {
        float s = st[kt][r] * 0.125f;
        if (key > rowb + r) s = -1e30f;
        st[kt][r] = s;
        mx[r] = fmaxf(mx[r], s);
      }
    }
#pragma unroll
    for (int r = 0; r < 4; r++) {
#pragma unroll
      for (int o = 1; o < 16; o <<= 1) mx[r] = fmaxf(mx[r], __shfl_xor(mx[r], o));
      float mn = fmaxf(m_[r], mx[r]);
      mx[r] = __expf(m_[r] - mn);  // alpha
      m_[r] = mn;
    }
    float rs[4] = {0.f, 0.f, 0.f, 0.f};
#pragma unroll
    for (int kt = 0; kt < 4; kt++)
#pragma unroll
      for (int r = 0; r < 4; r++) {
        float p = __expf(st[kt][r] - m_[r]);
        rs[r] += p;
        unsigned short phh = f2bf(p);
        Ph[w][(g * 4 + r) * 72 + kt * 16 + li] = phh;
        Pl[w][(g * 4 + r) * 72 + kt * 16 + li] = f2bf(p - bf2f(phh));
      }
#pragma unroll
    for (int r = 0; r < 4; r++) {
#pragma unroll
      for (int o = 1; o < 16; o <<= 1) rs[r] += __shfl_xor(rs[r], o);
      l_[r] = l_[r] * mx[r] + rs[r];
#pragma unroll
      for (int nt = 0; nt < 4; nt++) acc[nt][r] *= mx[r];
    }
    // ---- PV ----
    bf16x8 pfh[2], pfl[2];
#pragma unroll
    for (int kc = 0; kc < 2; kc++) {
      int po = li * 72 + kc * 32 + g * 8;
      pfh[kc] = *(const bf16x8*)&Ph[w][po];
      pfl[kc] = *(const bf16x8*)&Pl[w][po];
    }
#pragma unroll
    for (int nt = 0; nt < 4; nt++)
#pragma unroll
      for (int kc = 0; kc < 2; kc++) {
        int vo = (kc * 4 + g) * 512 + (nt * 16 + li) * 8;
        bf16x8 vh = *(const bf16x8*)&vth[vo];
        bf16x8 vl = *(const bf16x8*)&vtl[vo];
        acc[nt] = __builtin_amdgcn_mfma_f32_16x16x32_bf16(pfh[kc], vh, acc[nt], 0, 0, 0);
        acc[nt] = __builtin_amdgcn_mfma_f32_16x16x32_bf16(pfh[kc], vl, acc[nt], 0, 0, 0);
        acc[nt] = __builtin_amdgcn_mfma_f32_16x16x32_bf16(pfl[kc], vh, acc[nt], 0, 0, 0);
      }
  }
  size_t ybase = ((size_t)(b * Sn) + qt * 16) * (HQn * HDn) + h * HDn;
#pragma unroll
  for (int r = 0; r < 4; r++) {
    float inv = 1.f / l_[r];
#pragma unroll
    for (int nt = 0; nt < 4; nt++) {
      size_t idx = ybase + (size_t)(g * 4 + r) * (HQn * HDn) + nt * 16 + li;
      float v = acc[nt][r] * inv;
      unsigned short hi = f2bf(v);
      yh[idx] = hi;
      yl[idx] = f2bf(v - bf2f(hi));
    }
  }
}

// ---------------- MoE router: softmax top-2, one wave per token (f32) ----------------
__global__ __launch_bounds__(256) void k_router(
    const float* __restrict__ t, const float* __restrict__ gw_,
    int* __restrict__ idx, float* __restrict__ val, int* __restrict__ cnt) {
  int tok = blockIdx.x * 4 + (threadIdx.x >> 6);
  int lane = threadIdx.x & 63;
  const float* tr = t + (size_t)tok * Hn;
  float s[8] = {0, 0, 0, 0, 0, 0, 0, 0};
  for (int hh = lane; hh < Hn; hh += 64) {
    float tv = tr[hh];
    float4 g0 = *(const float4*)(gw_ + hh * 8);
    float4 g1 = *(const float4*)(gw_ + hh * 8 + 4);
    s[0] = fmaf(tv, g0.x, s[0]); s[1] = fmaf(tv, g0.y, s[1]);
    s[2] = fmaf(tv, g0.z, s[2]); s[3] = fmaf(tv, g0.w, s[3]);
    s[4] = fmaf(tv, g1.x, s[4]); s[5] = fmaf(tv, g1.y, s[5]);
    s[6] = fmaf(tv, g1.z, s[6]); s[7] = fmaf(tv, g1.w, s[7]);
  }
#pragma unroll
  for (int e = 0; e < 8; e++)
#pragma unroll
    for (int off = 32; off > 0; off >>= 1) s[e] += __shfl_xor(s[e], off);
  if (lane == 0) {
    float mx = s[0];
    for (int e = 1; e < 8; e++) mx = fmaxf(mx, s[e]);
    float p[8];
    for (int e = 0; e < 8; e++) p[e] = __expf(s[e] - mx);
    int e0 = 0;
    for (int e = 1; e < 8; e++) if (p[e] > p[e0]) e0 = e;
    int e1 = (e0 == 0) ? 1 : 0;
    for (int e = 0; e < 8; e++) if (e != e0 && p[e] > p[e1]) e1 = e;
    float v0 = p[e0], v1 = p[e1], inv = 1.f / (v0 + v1);
    idx[tok * 2] = e0; idx[tok * 2 + 1] = e1;
    val[tok * 2] = v0 * inv; val[tok * 2 + 1] = v1 * inv;
    atomicAdd(&cnt[e0], 1); atomicAdd(&cnt[e1], 1);
  }
}

__global__ void k_scan(const int* __restrict__ cnt, int* __restrict__ offs,
                       int* __restrict__ cursor) {
  if (threadIdx.x == 0) {
    int run = 0;
    for (int e = 0; e < En; e++) { offs[e] = run; cursor[e] = run; run += cnt[e]; }
  }
}

__global__ __launch_bounds__(256) void k_scatter(
    const int* __restrict__ idx, const float* __restrict__ val,
    int* __restrict__ cursor, int* __restrict__ tokl, float* __restrict__ wvl) {
  int t = blockIdx.x * 256 + threadIdx.x;
#pragma unroll
  for (int slot = 0; slot < 2; slot++) {
    int e = idx[t * 2 + slot];
    int pos = atomicAdd(&cursor[e], 1);
    tokl[pos] = t;
    wvl[pos] = val[t * 2 + slot];
  }
}

// ---------------- gather token rows (bf16) into routed order ----------------
__global__ __launch_bounds__(256) void k_gather(
    const unsigned short* __restrict__ tb, const int* __restrict__ tokl,
    unsigned short* __restrict__ tg) {
  int r = blockIdx.x;
  int tk = tokl[r];
  const ushort4* s = (const ushort4*)(tb + (size_t)tk * Hn);
  ushort4* d = (ushort4*)(tg + (size_t)r * Hn);
  d[threadIdx.x] = s[threadIdx.x];
}

// ---------------- MoE GEMM1 (MFMA): ug[r][0:4096] = tg[r] @ w13t[e]^T ----------------
// 128x128 tile, BK=32, 4 waves 2x2, STATIC double buffer (2x-unrolled K loop).
__global__ __launch_bounds__(256) void k_moe13(
    const unsigned short* __restrict__ tg, const unsigned short* __restrict__ w13t,
    unsigned short* __restrict__ ug, const int* __restrict__ cnt,
    const int* __restrict__ offs) {
  int e = blockIdx.z;
  int n_e = cnt[e];
  int mt = blockIdx.y;
  if (mt * 128 >= n_e) return;
  int base = offs[e];
  const unsigned short* A = tg + (size_t)(base + mt * 128) * Hn;
  const unsigned short* Bt = w13t + (size_t)e * (2 * In) * Hn;
  __shared__ __align__(16) short sA0[4096], sA1[4096];
  __shared__ __align__(16) short sB0[4096], sB1[4096];
  int tid = threadIdx.x;
  int wave = tid >> 6, lane = tid & 63;
  int n0 = blockIdx.x * 128;
  int wm = wave >> 1, wn = wave & 1;
  int r0s = ((tid >> 6) << 4) | (tid & 15), k0s = ((tid >> 4) & 3) * 8;
  int r1s = r0s + 64;
  const unsigned short* Ap0 = A + (size_t)r0s * Hn + k0s;
  const unsigned short* Ap1 = A + (size_t)r1s * Hn + k0s;
  const unsigned short* Bp0 = Bt + (size_t)(n0 + r0s) * Hn + k0s;
  const unsigned short* Bp1 = Bt + (size_t)(n0 + r1s) * Hn + k0s;
  size_t d0 = (size_t)tid * 8, d1 = (size_t)(256 + tid) * 8;
#define M13_STAGE(S, kb) do { \
    gll16(Ap0 + (kb), sA##S + d0); \
    gll16(Ap1 + (kb), sA##S + d1); \
    gll16(Bp0 + (kb), sB##S + d0); \
    gll16(Bp1 + (kb), sB##S + d1); \
  } while (0)
#define M13_COMP(S) do { \
    bf16x8 af[4], bfr[4]; \
    _Pragma("unroll") \
    for (int i = 0; i < 4; i++) \
      af[i] = *(const bf16x8*)(sA##S + ((wm * 4 + i) * 64 + lane) * 8); \
    _Pragma("unroll") \
    for (int j = 0; j < 4; j++) \
      bfr[j] = *(const bf16x8*)(sB##S + ((wn * 4 + j) * 64 + lane) * 8); \
    _Pragma("unroll") \
    for (int i = 0; i < 4; i++) \
      _Pragma("unroll") \
      for (int j = 0; j < 4; j++) \
        acc[i][j] = __builtin_amdgcn_mfma_f32_16x16x32_bf16(af[i], bfr[j], acc[i][j], 0, 0, 0); \
  } while (0)
  f32x4 zf = {0.f, 0.f, 0.f, 0.f};
  f32x4 acc[4][4];
#pragma unroll
  for (int i = 0; i < 4; i++)
#pragma unroll
    for (int j = 0; j < 4; j++) acc[i][j] = zf;
  M13_STAGE(0, 0);
  __syncthreads();
  for (int kb = 0; kb < Hn; kb += 64) {
    M13_STAGE(1, kb + 32);
    M13_COMP(0);
    __syncthreads();
    if (kb + 64 < Hn) M13_STAGE(0, kb + 64);
    M13_COMP(1);
    __syncthreads();
  }
#undef M13_STAGE
#undef M13_COMP
  int cr = (lane >> 4) * 4, cc = lane & 15;
#pragma unroll
  for (int i = 0; i < 4; i++) {
    int lrow0 = (wm * 4 + i) * 16 + cr;
#pragma unroll
    for (int j = 0; j < 4; j++) {
      int ncol = n0 + (wn * 4 + j) * 16 + cc;
#pragma unroll
      for (int r = 0; r < 4; r++) {
        int rr = mt * 128 + lrow0 + r;
        if (rr < n_e)
          ug[(size_t)(base + rr) * (2 * In) + ncol] = f2bf(acc[i][j][r]);
      }
    }
  }
}

// ---------------- act = silu(u) * g ----------------
__global__ __launch_bounds__(256) void k_act(
    const unsigned short* __restrict__ ug, unsigned short* __restrict__ act) {
  size_t p = ((size_t)blockIdx.x * 256 + threadIdx.x) * 8;
  size_t r = p >> 11;
  int c = (int)(p & 2047);
  const ushort4* up = (const ushort4*)(ug + r * 4096 + c);
  const ushort4* gp = (const ushort4*)(ug + r * 4096 + 2048 + c);
  ushort4* ap = (ushort4*)(act + r * 2048 + c);
#pragma unroll
  for (int h = 0; h < 2; h++) {
    ushort4 uu = up[h], gg = gp[h];
    ushort4 oo;
    float u0 = bf2f(uu.x), u1 = bf2f(uu.y), u2 = bf2f(uu.z), u3 = bf2f(uu.w);
    oo.x = f2bf(u0 / (1.f + __expf(-u0)) * bf2f(gg.x));
    oo.y = f2bf(u1 / (1.f + __expf(-u1)) * bf2f(gg.y));
    oo.z = f2bf(u2 / (1.f + __expf(-u2)) * bf2f(gg.z));
    oo.w = f2bf(u3 / (1.f + __expf(-u3)) * bf2f(gg.w));
    ap[h] = oo;
  }
}

// ---------------- MoE GEMM2 (MFMA): out0 += gate * (act @ w2t[e]^T) ----------------
// 128x128 tile, BK=32, 4 waves 2x2, STATIC double buffer (2x-unrolled K loop).
__global__ __launch_bounds__(256) void k_moe2(
    const unsigned short* __restrict__ act, const unsigned short* __restrict__ w2t,
    const int* __restrict__ cnt, const int* __restrict__ offs,
    const int* __restrict__ tokl, const float* __restrict__ wvl,
    float* __restrict__ out0) {
  int e = blockIdx.z;
  int n_e = cnt[e];
  int mt = blockIdx.y;
  if (mt * 128 >= n_e) return;
  int base = offs[e];
  __shared__ int ltok[128];
  __shared__ float lwv[128];
  int tid = threadIdx.x;
  if (tid < 128) {
    int rr = mt * 128 + tid;
    bool v = rr < n_e;
    ltok[tid] = v ? tokl[base + rr] : -1;
    lwv[tid] = v ? wvl[base + rr] : 0.f;
  }
  const unsigned short* A = act + (size_t)(base + mt * 128) * In;
  const unsigned short* Bt = w2t + (size_t)e * Hn * In;
  __shared__ __align__(16) short sA0[4096], sA1[4096];
  __shared__ __align__(16) short sB0[4096], sB1[4096];
  int wave = tid >> 6, lane = tid & 63;
  int n0 = blockIdx.x * 128;
  int wm = wave >> 1, wn = wave & 1;
  int r0s = ((tid >> 6) << 4) | (tid & 15), k0s = ((tid >> 4) & 3) * 8;
  int r1s = r0s + 64;
  const unsigned short* Ap0 = A + (size_t)r0s * In + k0s;
  const unsigned short* Ap1 = A + (size_t)r1s * In + k0s;
  const unsigned short* Bp0 = Bt + (size_t)(n0 + r0s) * In + k0s;
  const unsigned short* Bp1 = Bt + (size_t)(n0 + r1s) * In + k0s;
  size_t d0 = (size_t)tid * 8, d1 = (size_t)(256 + tid) * 8;
#define M2_STAGE(S, kb) do { \
    gll16(Ap0 + (kb), sA##S + d0); \
    gll16(Ap1 + (kb), sA##S + d1); \
    gll16(Bp0 + (kb), sB##S + d0); \
    gll16(Bp1 + (kb), sB##S + d1); \
  } while (0)
#define M2_COMP(S) do { \
    bf16x8 af[4], bfr[4]; \
    _Pragma("unroll") \
    for (int i = 0; i < 4; i++) \
      af[i] = *(const bf16x8*)(sA##S + ((wm * 4 + i) * 64 + lane) * 8); \
    _Pragma("unroll") \
    for (int j = 0; j < 4; j++) \
      bfr[j] = *(const bf16x8*)(sB##S + ((wn * 4 + j) * 64 + lane) * 8); \
    _Pragma("unroll") \
    for (int i = 0; i < 4; i++) \
      _Pragma("unroll") \
      for (int j = 0; j < 4; j++) \
        acc[i][j] = __builtin_amdgcn_mfma_f32_16x16x32_bf16(af[i], bfr[j], acc[i][j], 0, 0, 0); \
  } while (0)
  f32x4 zf = {0.f, 0.f, 0.f, 0.f};
  f32x4 acc[4][4];
#pragma unroll
  for (int i = 0; i < 4; i++)
#pragma unroll
    for (int j = 0; j < 4; j++) acc[i][j] = zf;
  M2_STAGE(0, 0);
  __syncthreads();
  for (int kb = 0; kb < In; kb += 64) {
    M2_STAGE(1, kb + 32);
    M2_COMP(0);
    __syncthreads();
    if (kb + 64 < In) M2_STAGE(0, kb + 64);
    M2_COMP(1);
    __syncthreads();
  }
#undef M2_STAGE
#undef M2_COMP
  int cr = (lane >> 4) * 4, cc = lane & 15;
#pragma unroll
  for (int i = 0; i < 4; i++) {
    int lrow0 = (wm * 4 + i) * 16 + cr;
#pragma unroll
    for (int j = 0; j < 4; j++) {
      int ncol = n0 + (wn * 4 + j) * 16 + cc;
#pragma unroll
      for (int r = 0; r < 4; r++) {
        int lrow = lrow0 + r;
        int tk = ltok[lrow];
        if (tk >= 0)
          atomicAdd(out0 + (size_t)tk * Hn + ncol, lwv[lrow] * acc[i][j][r]);
      }
    }
  }
}

// ---------------- launch ----------------
extern "C" void kernel_launch(void* const* d_in, const int* in_sizes, int n_in,
                              void* d_out, int out_size, void* d_ws, size_t ws_size,
                              hipStream_t stream) {
  (void)in_sizes; (void)n_in; (void)out_size; (void)ws_size;
  const float* x      = (const float*)d_in[0];
  const float* freq   = (const float*)d_in[1];
  const float* n1w    = (const float*)d_in[2];
  const float* n2w    = (const float*)d_in[3];
  const float* wq     = (const float*)d_in[4];
  const float* wk     = (const float*)d_in[5];
  const float* wvp    = (const float*)d_in[6];
  const float* wo     = (const float*)d_in[7];
  const float* qn_w   = (const float*)d_in[8];
  const float* kn_w   = (const float*)d_in[9];
  const float* gate_w = (const float*)d_in[10];
  const float* w1     = (const float*)d_in[11];
  const float* w2     = (const float*)d_in[12];
  const float* w3     = (const float*)d_in[13];

  float* out0  = (float*)d_out;
  float* k_out = out0 + (size_t)Tn * Hn;
  float* v_out = k_out + (size_t)Tn * HKVn * HDn;

  char* wsb = (char*)d_ws;
  unsigned short* w13t = (unsigned short*)(wsb + 0);            // 64 MB
  unsigned short* w2t  = (unsigned short*)(wsb + 67108864);     // 32 MB
  unsigned short* tbf  = (unsigned short*)(wsb + 100663296);    // 4 MB
  unsigned short* tg   = (unsigned short*)(wsb + 104857600);    // 8 MB
  // act region (16 MB @113,246,208): used late (after k_moe13). Early-phase overlay:
  // projection-weight hi/lo copies (10 MB), dead before k_act writes.
  unsigned short* wqkvt_h = (unsigned short*)(wsb + 113246208); // 3 MB  [1536][1024]
  unsigned short* wqkvt_l = (unsigned short*)(wsb + 116391936); // 3 MB
  unsigned short* wot_h   = (unsigned short*)(wsb + 119537664); // 2 MB  [1024][1024]
  unsigned short* wot_l   = (unsigned short*)(wsb + 121634816); // 2 MB
  unsigned short* act  = (unsigned short*)(wsb + 113246208);    // 16 MB (late phase)
  // U overlay @130,023,424 (32 MB): f32/bf16 attention path, later reused as ug
  unsigned short* hnh  = (unsigned short*)(wsb + 130023424);    // 4 MB
  unsigned short* hnl  = (unsigned short*)(wsb + 134217728);    // 4 MB
  float* qkv_raw = (float*)(wsb + 138412032);                   // 12 MB [2048][1536]
  float* q_t   = (float*)(wsb + 150994944);                     // 8 MB
  unsigned short* kT8h = (unsigned short*)(wsb + 159383552);    // 1 MB
  unsigned short* kT8l = (unsigned short*)(wsb + 160432128);    // 1 MB
  unsigned short* vT8h = (unsigned short*)(wsb + 161480704);    // 1 MB
  unsigned short* vT8l = (unsigned short*)(wsb + 162529280);    // 1 MB
  unsigned short* ug = (unsigned short*)(wsb + 130023424);      // overlays the above
  unsigned short* yh = (unsigned short*)(wsb + 163577856);      // 4 MB (not overlaid)
  unsigned short* yl = (unsigned short*)(wsb + 167772160);      // 4 MB
  float* y2    = (float*)(wsb + 171966464);                     // 8 MB
  float* t_norm = (float*)(wsb + 150994944);                    // overlays q_t (dead)
  char*  rtr   = wsb + 180355072;
  int*   idxb   = (int*)(rtr);
  float* valb   = (float*)(rtr + 16384);
  int*   cnt    = (int*)(rtr + 32768);
  int*   offs   = (int*)(rtr + 32768 + 128);
  int*   cursor = (int*)(rtr + 32768 + 256);
  int*   tokl   = (int*)(rtr + 32768 + 384);
  float* wvl    = (float*)(rtr + 32768 + 384 + 16384);

  // MoE weight transposes (hi-only bf16, unchanged)
  k_tcvt<<<dim3(32, 16, 8), 256, 0, stream>>>(w1, w13t, 1024, 2048,
                                              (size_t)1024 * 2048, (size_t)4096 * 1024);
  k_tcvt<<<dim3(32, 16, 8), 256, 0, stream>>>(w3, w13t + (size_t)2048 * 1024, 1024, 2048,
                                              (size_t)1024 * 2048, (size_t)4096 * 1024);
  k_tcvt<<<dim3(16, 32, 8), 256, 0, stream>>>(w2, w2t, 2048, 1024,
                                              (size_t)2048 * 1024, (size_t)1024 * 2048);
  // projection weight transposes (hi/lo bf16): wqkvt[n][k], n = [q|k|v] concat
  k_tcvt2<<<dim3(16, 16), 256, 0, stream>>>(wq, wqkvt_h, wqkvt_l, 1024, 1024);
  k_tcvt2<<<dim3(4, 16), 256, 0, stream>>>(wk, wqkvt_h + (size_t)1024 * 1024,
                                           wqkvt_l + (size_t)1024 * 1024, 1024, 256);
  k_tcvt2<<<dim3(4, 16), 256, 0, stream>>>(wvp, wqkvt_h + (size_t)1280 * 1024,
                                           wqkvt_l + (size_t)1280 * 1024, 1024, 256);
  k_tcvt2<<<dim3(16, 16), 256, 0, stream>>>(wo, wot_h, wot_l, 1024, 1024);

  hipMemsetAsync(cnt, 0, 8 * sizeof(int), stream);

  k_rmsnorm<<<Tn, 256, 0, stream>>>(x, n1w, hnh, hnl);
  // fused qkv projection: [2048 x 1536] = hn @ [wq|wk|wv], split-precision MFMA
  k_pgemm<<<dim3(12, 32), 256, 0, stream>>>(hnh, hnl, wqkvt_h, wqkvt_l,
                                            qkv_raw, 1536, 1024);
  k_qkv_post<<<(Tn * 24) / 4, 256, 0, stream>>>(qkv_raw, qn_w, kn_w,
                                                freq, q_t, kT8h, kT8l, vT8h, vT8l,
                                                k_out, v_out);
  k_attn_mfma<<<Bn * HKVn * 64, 256, 0, stream>>>(q_t, kT8h, kT8l, vT8h, vT8l, yh, yl);
  // output projection: [2048 x 1024] = y @ wo, split-precision MFMA
  k_pgemm<<<dim3(8, 32), 256, 0, stream>>>(yh, yl, wot_h, wot_l, y2, 1024, 1024);
  k_resid_norm<<<Tn, 256, 0, stream>>>(x, y2, n2w, out0, t_norm, tbf);
  k_router<<<Tn / 4, 256, 0, stream>>>(t_norm, gate_w, idxb, valb, cnt);
  k_scan<<<1, 64, 0, stream>>>(cnt, offs, cursor);
  k_scatter<<<Tn / 256, 256, 0, stream>>>(idxb, valb, cursor, tokl, wvl);
  k_gather<<<2 * Tn, 256, 0, stream>>>(tbf, tokl, tg);
  k_moe13<<<dim3(32, 16, 8), 256, 0, stream>>>(tg, w13t, ug, cnt, offs);
  k_act<<<4096, 256, 0, stream>>>(ug, act);
  k_moe2<<<dim3(8, 16, 8), 256, 0, stream>>>(act, w2t, cnt, offs, tokl, wvl, out0);
}

// Round 4
// 679.516 us; speedup vs baseline: 1.0282x; 1.0282x over previous
//
#include <hip/hip_runtime.h>
#include <hip/hip_bf16.h>

#define HQn 16
#define HKVn 4
#define HDn 64
#define Bn 2
#define Sn 1024
#define Hn 1024
#define En 8
#define In 2048
#define Tn 2048
#define EPSf 1e-6f

typedef __attribute__((ext_vector_type(8))) short bf16x8;
typedef __attribute__((ext_vector_type(4))) float f32x4;

// ---------------- helpers ----------------
__device__ __forceinline__ unsigned short f2bf(float f) {
  unsigned u = __float_as_uint(f);
  u += 0x7fffu + ((u >> 16) & 1u);
  return (unsigned short)(u >> 16);
}
__device__ __forceinline__ float bf2f(unsigned short u) {
  return __uint_as_float(((unsigned)u) << 16);
}
__device__ __forceinline__ void gll16(const void* g, void* l) {
  __builtin_amdgcn_global_load_lds(
      (const __attribute__((address_space(1))) void*)g,
      (__attribute__((address_space(3))) void*)l, 16, 0, 0);
}

// ---------------- transpose + f32->bf16: src[Z][R][C] -> dst[Z][C][R] ----------------
__global__ __launch_bounds__(256) void k_tcvt(
    const float* __restrict__ src, unsigned short* __restrict__ dst,
    int R, int C, size_t sZ, size_t dZ) {
  src += (size_t)blockIdx.z * sZ;
  dst += (size_t)blockIdx.z * dZ;
  int c0 = blockIdx.x * 64, r0 = blockIdx.y * 64;
  __shared__ float t[64][65];
  int tid = threadIdx.x;
  int lr = tid >> 4, lc = (tid & 15) * 4;
#pragma unroll
  for (int p = 0; p < 4; p++) {
    float4 v = *(const float4*)(src + (size_t)(r0 + lr + p * 16) * C + c0 + lc);
    t[lr + p * 16][lc + 0] = v.x; t[lr + p * 16][lc + 1] = v.y;
    t[lr + p * 16][lc + 2] = v.z; t[lr + p * 16][lc + 3] = v.w;
  }
  __syncthreads();
  int oc = tid >> 2;
  int seg = (tid & 3) * 16;
  unsigned pk[8];
#pragma unroll
  for (int j = 0; j < 8; j++) {
    unsigned short lo = f2bf(t[seg + 2 * j][oc]);
    unsigned short hi = f2bf(t[seg + 2 * j + 1][oc]);
    pk[j] = (unsigned)lo | ((unsigned)hi << 16);
  }
  uint4* dp = (uint4*)(dst + (size_t)(c0 + oc) * R + r0 + seg);
  dp[0] = make_uint4(pk[0], pk[1], pk[2], pk[3]);
  dp[1] = make_uint4(pk[4], pk[5], pk[6], pk[7]);
}

// ---------------- transpose + f32 -> (hi,lo) bf16: src[R][C] -> dsth/dstl[C][R] ------
__global__ __launch_bounds__(256) void k_tcvt2(
    const float* __restrict__ src, unsigned short* __restrict__ dsth,
    unsigned short* __restrict__ dstl, int R, int C) {
  int c0 = blockIdx.x * 64, r0 = blockIdx.y * 64;
  __shared__ float t[64][65];
  int tid = threadIdx.x;
  int lr = tid >> 4, lc = (tid & 15) * 4;
#pragma unroll
  for (int p = 0; p < 4; p++) {
    float4 v = *(const float4*)(src + (size_t)(r0 + lr + p * 16) * C + c0 + lc);
    t[lr + p * 16][lc + 0] = v.x; t[lr + p * 16][lc + 1] = v.y;
    t[lr + p * 16][lc + 2] = v.z; t[lr + p * 16][lc + 3] = v.w;
  }
  __syncthreads();
  int oc = tid >> 2;
  int seg = (tid & 3) * 16;
  unsigned pkh[8], pkl[8];
#pragma unroll
  for (int j = 0; j < 8; j++) {
    float a = t[seg + 2 * j][oc], b = t[seg + 2 * j + 1][oc];
    unsigned short ahh = f2bf(a), bhh = f2bf(b);
    unsigned short alo = f2bf(a - bf2f(ahh)), blo = f2bf(b - bf2f(bhh));
    pkh[j] = (unsigned)ahh | ((unsigned)bhh << 16);
    pkl[j] = (unsigned)alo | ((unsigned)blo << 16);
  }
  size_t db = (size_t)(c0 + oc) * R + r0 + seg;
  uint4* dph = (uint4*)(dsth + db);
  dph[0] = make_uint4(pkh[0], pkh[1], pkh[2], pkh[3]);
  dph[1] = make_uint4(pkh[4], pkh[5], pkh[6], pkh[7]);
  uint4* dpl = (uint4*)(dstl + db);
  dpl[0] = make_uint4(pkl[0], pkl[1], pkl[2], pkl[3]);
  dpl[1] = make_uint4(pkl[4], pkl[5], pkl[6], pkl[7]);
}

// ---------------- RMSNorm over H=1024, one block per row -> hi/lo bf16 ----------------
__global__ __launch_bounds__(256) void k_rmsnorm(
    const float* __restrict__ x, const float* __restrict__ w,
    unsigned short* __restrict__ outh, unsigned short* __restrict__ outl) {
  int row = blockIdx.x, tid = threadIdx.x;
  size_t off = (size_t)row * Hn + tid * 4;
  float4 v = *(const float4*)(x + off);
  float ss = v.x * v.x + v.y * v.y + v.z * v.z + v.w * v.w;
#pragma unroll
  for (int o = 32; o > 0; o >>= 1) ss += __shfl_xor(ss, o);
  __shared__ float ls[4];
  if ((tid & 63) == 0) ls[tid >> 6] = ss;
  __syncthreads();
  float tot = ls[0] + ls[1] + ls[2] + ls[3];
  float sc = rsqrtf(tot * (1.0f / Hn) + EPSf);
  float4 wv = *(const float4*)(w + tid * 4);
  float o0 = v.x * sc * wv.x, o1 = v.y * sc * wv.y;
  float o2 = v.z * sc * wv.z, o3 = v.w * sc * wv.w;
  ushort4 h4, l4;
  h4.x = f2bf(o0); l4.x = f2bf(o0 - bf2f(h4.x));
  h4.y = f2bf(o1); l4.y = f2bf(o1 - bf2f(h4.y));
  h4.z = f2bf(o2); l4.z = f2bf(o2 - bf2f(h4.z));
  h4.w = f2bf(o3); l4.w = f2bf(o3 - bf2f(h4.w));
  *(ushort4*)(outh + off) = h4;
  *(ushort4*)(outl + off) = l4;
}

// ---------------- residual add + RMSNorm (f32 outs + bf16 copy of t) ----------------
__global__ __launch_bounds__(256) void k_resid_norm(
    const float* __restrict__ x, const float* __restrict__ y,
    const float* __restrict__ w, float* __restrict__ x2out,
    float* __restrict__ tout, unsigned short* __restrict__ tbf) {
  int row = blockIdx.x, tid = threadIdx.x;
  size_t off = (size_t)row * Hn + tid * 4;
  float4 xv = *(const float4*)(x + off);
  float4 yv = *(const float4*)(y + off);
  float4 s;
  s.x = xv.x + yv.x; s.y = xv.y + yv.y; s.z = xv.z + yv.z; s.w = xv.w + yv.w;
  *(float4*)(x2out + off) = s;
  float ss = s.x * s.x + s.y * s.y + s.z * s.z + s.w * s.w;
#pragma unroll
  for (int o = 32; o > 0; o >>= 1) ss += __shfl_xor(ss, o);
  __shared__ float ls[4];
  if ((tid & 63) == 0) ls[tid >> 6] = ss;
  __syncthreads();
  float tot = ls[0] + ls[1] + ls[2] + ls[3];
  float sc = rsqrtf(tot * (1.0f / Hn) + EPSf);
  float4 wv4 = *(const float4*)(w + tid * 4);
  float4 t4;
  t4.x = s.x * sc * wv4.x; t4.y = s.y * sc * wv4.y;
  t4.z = s.z * sc * wv4.z; t4.w = s.w * sc * wv4.w;
  *(float4*)(tout + off) = t4;
  ushort4 b4;
  b4.x = f2bf(t4.x); b4.y = f2bf(t4.y); b4.z = f2bf(t4.z); b4.w = f2bf(t4.w);
  *(ushort4*)(tbf + off) = b4;
}

// ---------------- split-precision MFMA GEMM: C(MxN f32) = A @ B^T -------------------
// A given as hi/lo bf16 [M][K]; B given as hi/lo bf16 [N][K] (k-contiguous).
// Block tile: (MT*32) x 128, BK=32, 4 waves 2x2, double-buffered 2-phase prefetch.
template<int MT>
__global__ __launch_bounds__(256) void k_pgemm(
    const unsigned short* __restrict__ Ah, const unsigned short* __restrict__ Al,
    const unsigned short* __restrict__ Bth, const unsigned short* __restrict__ Btl,
    float* __restrict__ C, int N, int K) {
  constexpr int BM = MT * 32;
  constexpr int ASL = BM * 32;  // shorts per A buffer
  __shared__ __align__(16) short smAh[2][ASL], smAl[2][ASL];
  __shared__ __align__(16) short smBh[2][4096], smBl[2][4096];
  int tid = threadIdx.x, wave = tid >> 6, lane = tid & 63;
  int n0 = blockIdx.x * 128, m0 = blockIdx.y * BM;
  int wm = wave >> 1, wn = wave & 1;
  int r0 = ((tid >> 6) << 4) | (tid & 15);
  int k0 = ((tid >> 4) & 3) * 8;
  int r1 = r0 + 64;
  const unsigned short* pAh0 = Ah + (size_t)(m0 + r0) * K + k0;
  const unsigned short* pAl0 = Al + (size_t)(m0 + r0) * K + k0;
  const unsigned short* pBh0 = Bth + (size_t)(n0 + r0) * K + k0;
  const unsigned short* pBl0 = Btl + (size_t)(n0 + r0) * K + k0;
  const unsigned short* pBh1 = Bth + (size_t)(n0 + r1) * K + k0;
  const unsigned short* pBl1 = Btl + (size_t)(n0 + r1) * K + k0;
  const unsigned short* pAh1 = pAh0;
  const unsigned short* pAl1 = pAl0;
  if constexpr (MT == 4) {
    pAh1 = Ah + (size_t)(m0 + r1) * K + k0;
    pAl1 = Al + (size_t)(m0 + r1) * K + k0;
  }
  int d0 = tid * 8, d1 = (256 + tid) * 8;
  auto STAGE = [&](int b, int kb) {
    gll16(pAh0 + kb, &smAh[b][d0]);
    gll16(pAl0 + kb, &smAl[b][d0]);
    if constexpr (MT == 4) {
      gll16(pAh1 + kb, &smAh[b][d1]);
      gll16(pAl1 + kb, &smAl[b][d1]);
    }
    gll16(pBh0 + kb, &smBh[b][d0]);
    gll16(pBl0 + kb, &smBl[b][d0]);
    gll16(pBh1 + kb, &smBh[b][d1]);
    gll16(pBl1 + kb, &smBl[b][d1]);
  };
  f32x4 zf = {0.f, 0.f, 0.f, 0.f};
  f32x4 acc[MT][4];
#pragma unroll
  for (int i = 0; i < MT; i++)
#pragma unroll
    for (int j = 0; j < 4; j++) acc[i][j] = zf;
  STAGE(0, 0);
  __syncthreads();
  for (int kb = 0; kb < K; kb += 32) {
    int cur = (kb >> 5) & 1;
    if (kb + 32 < K) STAGE(cur ^ 1, kb + 32);
    bf16x8 ah[MT], al[MT], bh[4], bl[4];
#pragma unroll
    for (int i = 0; i < MT; i++) {
      ah[i] = *(const bf16x8*)&smAh[cur][((wm * MT + i) * 64 + lane) * 8];
      al[i] = *(const bf16x8*)&smAl[cur][((wm * MT + i) * 64 + lane) * 8];
    }
#pragma unroll
    for (int j = 0; j < 4; j++) {
      bh[j] = *(const bf16x8*)&smBh[cur][((wn * 4 + j) * 64 + lane) * 8];
      bl[j] = *(const bf16x8*)&smBl[cur][((wn * 4 + j) * 64 + lane) * 8];
    }
#pragma unroll
    for (int i = 0; i < MT; i++)
#pragma unroll
      for (int j = 0; j < 4; j++) {
        acc[i][j] = __builtin_amdgcn_mfma_f32_16x16x32_bf16(ah[i], bh[j], acc[i][j], 0, 0, 0);
        acc[i][j] = __builtin_amdgcn_mfma_f32_16x16x32_bf16(ah[i], bl[j], acc[i][j], 0, 0, 0);
        acc[i][j] = __builtin_amdgcn_mfma_f32_16x16x32_bf16(al[i], bh[j], acc[i][j], 0, 0, 0);
      }
    __syncthreads();
  }
  int cr = (lane >> 4) * 4, cc = lane & 15;
#pragma unroll
  for (int i = 0; i < MT; i++) {
    int row0 = m0 + (wm * MT + i) * 16 + cr;
#pragma unroll
    for (int j = 0; j < 4; j++) {
      int col = n0 + (wn * 4 + j) * 16 + cc;
#pragma unroll
      for (int r = 0; r < 4; r++)
        C[(size_t)(row0 + r) * N + col] = acc[i][j][r];
    }
  }
}

// ---------------- q/k head-RMSNorm + RoPE; emits q_t f32, K/V split-bf16 swizzled ----
// input qkv: [token][1536] = [q 0..1023 | k 1024..1279 | v 1280..1535]
__global__ __launch_bounds__(256) void k_qkv_post(
    const float* __restrict__ qkv, const float* __restrict__ qn_w,
    const float* __restrict__ kn_w, const float* __restrict__ freq,
    float* __restrict__ q_t,
    unsigned short* __restrict__ kT8h, unsigned short* __restrict__ kT8l,
    unsigned short* __restrict__ vT8h, unsigned short* __restrict__ vT8l,
    float* __restrict__ k_out, float* __restrict__ v_out) {
  int gw = blockIdx.x * 4 + (threadIdx.x >> 6);
  int lane = threadIdx.x & 63;
  int token = gw / 24;
  int hh = gw % 24;
  int b = token / Sn, s = token % Sn;
  if (hh >= 20) {  // v head
    int h = hh - 20;
    float v = qkv[(size_t)token * 1536 + 1280 + h * HDn + lane];
    unsigned short hi = f2bf(v);
    unsigned short lo = f2bf(v - bf2f(hi));
    size_t vb = (((size_t)(b * HKVn + h) * 128 + (s >> 3)) * 64 + lane) * 8 + (s & 7);
    vT8h[vb] = hi; vT8l[vb] = lo;
    v_out[(size_t)token * (HKVn * HDn) + h * HDn + lane] = v;
    return;
  }
  bool isq = hh < 16;
  int h = isq ? hh : hh - 16;
  float val = isq ? qkv[(size_t)token * 1536 + h * HDn + lane]
                  : qkv[(size_t)token * 1536 + 1024 + h * HDn + lane];
  float ss = val * val;
#pragma unroll
  for (int o = 32; o > 0; o >>= 1) ss += __shfl_xor(ss, o);
  float scn = rsqrtf(ss * (1.0f / HDn) + EPSf);
  float w = isq ? qn_w[lane] : kn_w[lane];
  float xn = val * scn * w;
  float f = freq[(size_t)s * (HDn / 2) + (lane & 31)];
  float c = cosf(f), sn = sinf(f);
  float partner = __shfl_xor(xn, 32);
  float out = (lane < 32) ? (xn * c - partner * sn) : (partner * sn + xn * c);
  if (isq) {
    q_t[(((size_t)(b * HQn + h)) * Sn + s) * HDn + lane] = out;
  } else {
    unsigned short hi = f2bf(out);
    unsigned short lo = f2bf(out - bf2f(hi));
    size_t kb = (((size_t)(b * HKVn + h) * 8 + (lane >> 3)) * Sn + s) * 8 + (lane & 7);
    kT8h[kb] = hi; kT8l[kb] = lo;
    k_out[(size_t)token * (HKVn * HDn) + h * HDn + lane] = out;
  }
}

// ---------------- MFMA flash attention, split-precision (hi/lo bf16 = ~f32 exact) ----
__global__ __launch_bounds__(256) void k_attn_mfma(
    const float* __restrict__ q_t,
    const unsigned short* __restrict__ kT8h, const unsigned short* __restrict__ kT8l,
    const unsigned short* __restrict__ vT8h, const unsigned short* __restrict__ vT8l,
    unsigned short* __restrict__ yh, unsigned short* __restrict__ yl) {
  __shared__ __align__(16) unsigned short klh[4096], kll[4096];  // [do][key][din]
  __shared__ __align__(16) unsigned short vth[4096], vtl[4096];  // [ko][d][kin]
  __shared__ __align__(16) unsigned short Ph[4][1152], Pl[4][1152];  // [w][row][72]
  int bid = blockIdx.x;
  int qt = 63 - (bid & 63);       // long blocks first
  int kvh = (bid >> 6) & 3;
  int b = bid >> 8;
  int tid = threadIdx.x, w = tid >> 6, lane = tid & 63;
  int h = kvh * 4 + w;
  int g = lane >> 4, li = lane & 15;
  const float* qrow = q_t + (((size_t)(b * HQn + h) * Sn) + qt * 16 + li) * HDn + g * 8;
  bf16x8 qh[2], ql[2];
#pragma unroll
  for (int kc = 0; kc < 2; kc++) {
    float v[8];
    *(float4*)(v) = *(const float4*)(qrow + kc * 32);
    *(float4*)(v + 4) = *(const float4*)(qrow + kc * 32 + 4);
#pragma unroll
    for (int j = 0; j < 8; j++) {
      unsigned short hi = f2bf(v[j]);
      qh[kc][j] = (short)hi;
      ql[kc][j] = (short)f2bf(v[j] - bf2f(hi));
    }
  }
  size_t bh = (size_t)(b * HKVn + kvh) * 65536;
  f32x4 acc[4];
  f32x4 zf = {0.f, 0.f, 0.f, 0.f};
#pragma unroll
  for (int nt = 0; nt < 4; nt++) acc[nt] = zf;
  float m_[4] = {-1e30f, -1e30f, -1e30f, -1e30f};
  float l_[4] = {0.f, 0.f, 0.f, 0.f};
  int rowb = qt * 16 + g * 4;
  int kmax = qt * 16 + 15;
  for (int kk = 0; kk <= kmax; kk += 64) {
    __syncthreads();
#pragma unroll
    for (int i = 0; i < 2; i++) {
      int idx = w * 2 + i;
      gll16(kT8h + bh + (size_t)idx * 8192 + (size_t)kk * 8 + lane * 8, &klh[idx * 512]);
      gll16(kT8l + bh + (size_t)idx * 8192 + (size_t)kk * 8 + lane * 8, &kll[idx * 512]);
      gll16(vT8h + bh + (size_t)(kk / 8 + idx) * 512 + lane * 8, &vth[idx * 512]);
      gll16(vT8l + bh + (size_t)(kk / 8 + idx) * 512 + lane * 8, &vtl[idx * 512]);
    }
    __syncthreads();
    // ---- scores: 4 key-tiles of 16 ----
    f32x4 st[4];
#pragma unroll
    for (int kt = 0; kt < 4; kt++) st[kt] = zf;
#pragma unroll
    for (int kt = 0; kt < 4; kt++)
#pragma unroll
      for (int kc = 0; kc < 2; kc++) {
        int ko = (kc * 4 + g) * 512 + (kt * 16 + li) * 8;
        bf16x8 kh = *(const bf16x8*)&klh[ko];
        bf16x8 klo = *(const bf16x8*)&kll[ko];
        st[kt] = __builtin_amdgcn_mfma_f32_16x16x32_bf16(qh[kc], kh, st[kt], 0, 0, 0);
        st[kt] = __builtin_amdgcn_mfma_f32_16x16x32_bf16(qh[kc], klo, st[kt], 0, 0, 0);
        st[kt] = __builtin_amdgcn_mfma_f32_16x16x32_bf16(ql[kc], kh, st[kt], 0, 0, 0);
      }
    // ---- online softmax (rows rowb..rowb+3 per lane) ----
    float mx[4] = {-1e30f, -1e30f, -1e30f, -1e30f};
#pragma unroll
    for (int kt = 0; kt < 4; kt++) {
      int key = kk + kt * 16 + li;
#pragma unroll
      for (int r = 0; r < 4; r++) {
        float s = st[kt][r] * 0.125f;
        if (key > rowb + r) s = -1e30f;
        st[kt][r] = s;
        mx[r] = fmaxf(mx[r], s);
      }
    }
#pragma unroll
    for (int r = 0; r < 4; r++) {
#pragma unroll
      for (int o = 1; o < 16; o <<= 1) mx[r] = fmaxf(mx[r], __shfl_xor(mx[r], o));
      float mn = fmaxf(m_[r], mx[r]);
      mx[r] = __expf(m_[r] - mn);  // alpha
      m_[r] = mn;
    }
    float rs[4] = {0.f, 0.f, 0.f, 0.f};
#pragma unroll
    for (int kt = 0; kt < 4; kt++)
#pragma unroll
      for (int r = 0; r < 4; r++) {
        float p = __expf(st[kt][r] - m_[r]);
        rs[r] += p;
        unsigned short phh = f2bf(p);
        Ph[w][(g * 4 + r) * 72 + kt * 16 + li] = phh;
        Pl[w][(g * 4 + r) * 72 + kt * 16 + li] = f2bf(p - bf2f(phh));
      }
#pragma unroll
    for (int r = 0; r < 4; r++) {
#pragma unroll
      for (int o = 1; o < 16; o <<= 1) rs[r] += __shfl_xor(rs[r], o);
      l_[r] = l_[r] * mx[r] + rs[r];
#pragma unroll
      for (int nt = 0; nt < 4; nt++) acc[nt][r] *= mx[r];
    }
    // ---- PV ----
    bf16x8 pfh[2], pfl[2];
#pragma unroll
    for (int kc = 0; kc < 2; kc++) {
      int po = li * 72 + kc * 32 + g * 8;
      pfh[kc] = *(const bf16x8*)&Ph[w][po];
      pfl[kc] = *(const bf16x8*)&Pl[w][po];
    }
#pragma unroll
    for (int nt = 0; nt < 4; nt++)
#pragma unroll
      for (int kc = 0; kc < 2; kc++) {
        int vo = (kc * 4 + g) * 512 + (nt * 16 + li) * 8;
        bf16x8 vh = *(const bf16x8*)&vth[vo];
        bf16x8 vl = *(const bf16x8*)&vtl[vo];
        acc[nt] = __builtin_amdgcn_mfma_f32_16x16x32_bf16(pfh[kc], vh, acc[nt], 0, 0, 0);
        acc[nt] = __builtin_amdgcn_mfma_f32_16x16x32_bf16(pfh[kc], vl, acc[nt], 0, 0, 0);
        acc[nt] = __builtin_amdgcn_mfma_f32_16x16x32_bf16(pfl[kc], vh, acc[nt], 0, 0, 0);
      }
  }
  size_t ybase = ((size_t)(b * Sn) + qt * 16) * (HQn * HDn) + h * HDn;
#pragma unroll
  for (int r = 0; r < 4; r++) {
    float inv = 1.f / l_[r];
#pragma unroll
    for (int nt = 0; nt < 4; nt++) {
      size_t idx = ybase + (size_t)(g * 4 + r) * (HQn * HDn) + nt * 16 + li;
      float v = acc[nt][r] * inv;
      unsigned short hi = f2bf(v);
      yh[idx] = hi;
      yl[idx] = f2bf(v - bf2f(hi));
    }
  }
}

// ---------------- MoE router: softmax top-2, one wave per token (f32) ----------------
__global__ __launch_bounds__(256) void k_router(
    const float* __restrict__ t, const float* __restrict__ gw_,
    int* __restrict__ idx, float* __restrict__ val, int* __restrict__ cnt) {
  int tok = blockIdx.x * 4 + (threadIdx.x >> 6);
  int lane = threadIdx.x & 63;
  const float* tr = t + (size_t)tok * Hn;
  float s[8] = {0, 0, 0, 0, 0, 0, 0, 0};
  for (int hh = lane; hh < Hn; hh += 64) {
    float tv = tr[hh];
    float4 g0 = *(const float4*)(gw_ + hh * 8);
    float4 g1 = *(const float4*)(gw_ + hh * 8 + 4);
    s[0] = fmaf(tv, g0.x, s[0]); s[1] = fmaf(tv, g0.y, s[1]);
    s[2] = fmaf(tv, g0.z, s[2]); s[3] = fmaf(tv, g0.w, s[3]);
    s[4] = fmaf(tv, g1.x, s[4]); s[5] = fmaf(tv, g1.y, s[5]);
    s[6] = fmaf(tv, g1.z, s[6]); s[7] = fmaf(tv, g1.w, s[7]);
  }
#pragma unroll
  for (int e = 0; e < 8; e++)
#pragma unroll
    for (int off = 32; off > 0; off >>= 1) s[e] += __shfl_xor(s[e], off);
  if (lane == 0) {
    float mx = s[0];
    for (int e = 1; e < 8; e++) mx = fmaxf(mx, s[e]);
    float p[8];
    for (int e = 0; e < 8; e++) p[e] = __expf(s[e] - mx);
    int e0 = 0;
    for (int e = 1; e < 8; e++) if (p[e] > p[e0]) e0 = e;
    int e1 = (e0 == 0) ? 1 : 0;
    for (int e = 0; e < 8; e++) if (e != e0 && p[e] > p[e1]) e1 = e;
    float v0 = p[e0], v1 = p[e1], inv = 1.f / (v0 + v1);
    idx[tok * 2] = e0; idx[tok * 2 + 1] = e1;
    val[tok * 2] = v0 * inv; val[tok * 2 + 1] = v1 * inv;
    atomicAdd(&cnt[e0], 1); atomicAdd(&cnt[e1], 1);
  }
}

__global__ void k_scan(const int* __restrict__ cnt, int* __restrict__ offs,
                       int* __restrict__ cursor) {
  if (threadIdx.x == 0) {
    int run = 0;
    for (int e = 0; e < En; e++) { offs[e] = run; cursor[e] = run; run += cnt[e]; }
  }
}

__global__ __launch_bounds__(256) void k_scatter(
    const int* __restrict__ idx, const float* __restrict__ val,
    int* __restrict__ cursor, int* __restrict__ tokl, float* __restrict__ wvl) {
  int t = blockIdx.x * 256 + threadIdx.x;
#pragma unroll
  for (int slot = 0; slot < 2; slot++) {
    int e = idx[t * 2 + slot];
    int pos = atomicAdd(&cursor[e], 1);
    tokl[pos] = t;
    wvl[pos] = val[t * 2 + slot];
  }
}

// ---------------- gather token rows (bf16) into routed order ----------------
__global__ __launch_bounds__(256) void k_gather(
    const unsigned short* __restrict__ tb, const int* __restrict__ tokl,
    unsigned short* __restrict__ tg) {
  int r = blockIdx.x;
  int tk = tokl[r];
  const ushort4* s = (const ushort4*)(tb + (size_t)tk * Hn);
  ushort4* d = (ushort4*)(tg + (size_t)r * Hn);
  d[threadIdx.x] = s[threadIdx.x];
}

// ---------------- MoE GEMM1 (MFMA): ug[r][0:4096] = tg[r] @ w13t[e]^T ----------------
// 256x256 tile, BK=64, 8 waves (2x4, wave-tile 128x64), static dbuf, 128 KB LDS.
// Mechanism: 64 MFMA/wave per K-step (~1300 CU-cyc/block-step of matrix work)
// swallows the staged-tile VMEM latency that 128-tiles could not (R2/R3 nulls).
__global__ __launch_bounds__(512) void k_moe13(
    const unsigned short* __restrict__ tg, const unsigned short* __restrict__ w13t,
    unsigned short* __restrict__ ug, const int* __restrict__ cnt,
    const int* __restrict__ offs) {
  int e = blockIdx.z;
  int n_e = cnt[e];
  int mt = blockIdx.y;
  if (mt * 256 >= n_e) return;
  int base = offs[e];
  int n0 = blockIdx.x * 256;
  const unsigned short* A = tg + (size_t)(base + mt * 256) * Hn;
  const unsigned short* Bt = w13t + (size_t)e * (2 * In) * Hn + (size_t)n0 * Hn;
  __shared__ __align__(16) short sA0[16384], sA1[16384];
  __shared__ __align__(16) short sB0[16384], sB1[16384];
  int tid = threadIdx.x;
  int wave = tid >> 6, lane = tid & 63;
  int wm = wave >> 2, wn = wave & 3;
  int rowLo = ((tid >> 6) << 4) | (tid & 15);   // 0..127 (but tid>>6 up to 7 -> 0..127)
  int kLo = ((tid >> 4) & 3) * 8;               // 0,8,16,24
  const unsigned short* a0 = A + (size_t)rowLo * Hn + kLo;
  const unsigned short* a1 = A + (size_t)(rowLo + 128) * Hn + kLo;
  const unsigned short* b0 = Bt + (size_t)rowLo * Hn + kLo;
  const unsigned short* b1 = Bt + (size_t)(rowLo + 128) * Hn + kLo;
  size_t d0 = (size_t)tid * 8;
  // LDS layout per buffer: [half k (2)][rowblk (16)][oct (4)][row&15 (16)] x8 shorts
#define M13_STAGE(S, kb) do { \
    gll16(a0 + (kb), sA##S + d0); \
    gll16(a1 + (kb), sA##S + 4096 + d0); \
    gll16(a0 + (kb) + 32, sA##S + 8192 + d0); \
    gll16(a1 + (kb) + 32, sA##S + 12288 + d0); \
    gll16(b0 + (kb), sB##S + d0); \
    gll16(b1 + (kb), sB##S + 4096 + d0); \
    gll16(b0 + (kb) + 32, sB##S + 8192 + d0); \
    gll16(b1 + (kb) + 32, sB##S + 12288 + d0); \
  } while (0)
#define M13_COMP(S) do { \
    _Pragma("unroll") \
    for (int kk = 0; kk < 2; kk++) { \
      bf16x8 af[8], bfr[4]; \
      _Pragma("unroll") \
      for (int i = 0; i < 8; i++) \
        af[i] = *(const bf16x8*)(sA##S + kk * 8192 + ((wm * 8 + i) * 64 + lane) * 8); \
      _Pragma("unroll") \
      for (int j = 0; j < 4; j++) \
        bfr[j] = *(const bf16x8*)(sB##S + kk * 8192 + ((wn * 4 + j) * 64 + lane) * 8); \
      _Pragma("unroll") \
      for (int i = 0; i < 8; i++) \
        _Pragma("unroll") \
        for (int j = 0; j < 4; j++) \
          acc[i][j] = __builtin_amdgcn_mfma_f32_16x16x32_bf16(af[i], bfr[j], acc[i][j], 0, 0, 0); \
    } \
  } while (0)
  f32x4 zf = {0.f, 0.f, 0.f, 0.f};
  f32x4 acc[8][4];
#pragma unroll
  for (int i = 0; i < 8; i++)
#pragma unroll
    for (int j = 0; j < 4; j++) acc[i][j] = zf;
  M13_STAGE(0, 0);
  __syncthreads();
  for (int kb = 0; kb < Hn; kb += 128) {
    M13_STAGE(1, kb + 64);
    M13_COMP(0);
    __syncthreads();
    if (kb + 128 < Hn) M13_STAGE(0, kb + 128);
    M13_COMP(1);
    __syncthreads();
  }
#undef M13_STAGE
#undef M13_COMP
  int cr = (lane >> 4) * 4, cc = lane & 15;
#pragma unroll
  for (int i = 0; i < 8; i++) {
    int lrow0 = wm * 128 + i * 16 + cr;
#pragma unroll
    for (int j = 0; j < 4; j++) {
      int ncol = n0 + wn * 64 + j * 16 + cc;
#pragma unroll
      for (int r = 0; r < 4; r++) {
        int rr = mt * 256 + lrow0 + r;
        if (rr < n_e)
          ug[(size_t)(base + rr) * (2 * In) + ncol] = f2bf(acc[i][j][r]);
      }
    }
  }
}

// ---------------- act = silu(u) * g ----------------
__global__ __launch_bounds__(256) void k_act(
    const unsigned short* __restrict__ ug, unsigned short* __restrict__ act) {
  size_t p = ((size_t)blockIdx.x * 256 + threadIdx.x) * 8;
  size_t r = p >> 11;
  int c = (int)(p & 2047);
  const ushort4* up = (const ushort4*)(ug + r * 4096 + c);
  const ushort4* gp = (const ushort4*)(ug + r * 4096 + 2048 + c);
  ushort4* ap = (ushort4*)(act + r * 2048 + c);
#pragma unroll
  for (int h = 0; h < 2; h++) {
    ushort4 uu = up[h], gg = gp[h];
    ushort4 oo;
    float u0 = bf2f(uu.x), u1 = bf2f(uu.y), u2 = bf2f(uu.z), u3 = bf2f(uu.w);
    oo.x = f2bf(u0 / (1.f + __expf(-u0)) * bf2f(gg.x));
    oo.y = f2bf(u1 / (1.f + __expf(-u1)) * bf2f(gg.y));
    oo.z = f2bf(u2 / (1.f + __expf(-u2)) * bf2f(gg.z));
    oo.w = f2bf(u3 / (1.f + __expf(-u3)) * bf2f(gg.w));
    ap[h] = oo;
  }
}

// ---------------- MoE GEMM2 (MFMA): out0 += gate * (act @ w2t[e]^T) ----------------
// 128x128 tile, BK=32, 8 waves (4x2, wave-tile 32x64), double-buffered prefetch.
__global__ __launch_bounds__(512) void k_moe2(
    const unsigned short* __restrict__ act, const unsigned short* __restrict__ w2t,
    const int* __restrict__ cnt, const int* __restrict__ offs,
    const int* __restrict__ tokl, const float* __restrict__ wvl,
    float* __restrict__ out0) {
  int e = blockIdx.z;
  int n_e = cnt[e];
  int mt = blockIdx.y;
  if (mt * 128 >= n_e) return;
  int base = offs[e];
  __shared__ int ltok[128];
  __shared__ float lwv[128];
  int tid = threadIdx.x;
  if (tid < 128) {
    int rr = mt * 128 + tid;
    bool v = rr < n_e;
    ltok[tid] = v ? tokl[base + rr] : -1;
    lwv[tid] = v ? wvl[base + rr] : 0.f;
  }
  const unsigned short* A = act + (size_t)(base + mt * 128) * In;
  const unsigned short* Bt = w2t + (size_t)e * Hn * In;
  __shared__ __align__(16) short smA[2][4096];
  __shared__ __align__(16) short smB[2][4096];
  int wave = tid >> 6, lane = tid & 63;
  int n0 = blockIdx.x * 128;
  int wm = wave >> 1, wn = wave & 1;
  int r0s = ((tid >> 6) << 4) | (tid & 15);
  int k0s = ((tid >> 4) & 3) * 8;
  const unsigned short* ApA = A + (size_t)r0s * In + k0s;
  const unsigned short* BpB = Bt + (size_t)(n0 + r0s) * In + k0s;
  auto STAGE = [&](int b, int kb) {
    gll16(ApA + kb, &smA[b][tid * 8]);
    gll16(BpB + kb, &smB[b][tid * 8]);
  };
  f32x4 zf = {0.f, 0.f, 0.f, 0.f};
  f32x4 acc[2][4];
#pragma unroll
  for (int i = 0; i < 2; i++)
#pragma unroll
    for (int j = 0; j < 4; j++) acc[i][j] = zf;
  STAGE(0, 0);
  __syncthreads();
  for (int kb = 0; kb < In; kb += 32) {
    int cur = (kb >> 5) & 1;
    if (kb + 32 < In) STAGE(cur ^ 1, kb + 32);
    bf16x8 af[2], bfr[4];
#pragma unroll
    for (int i = 0; i < 2; i++)
      af[i] = *(const bf16x8*)&smA[cur][((wm * 2 + i) * 64 + lane) * 8];
#pragma unroll
    for (int j = 0; j < 4; j++)
      bfr[j] = *(const bf16x8*)&smB[cur][((wn * 4 + j) * 64 + lane) * 8];
#pragma unroll
    for (int i = 0; i < 2; i++)
#pragma unroll
      for (int j = 0; j < 4; j++)
        acc[i][j] = __builtin_amdgcn_mfma_f32_16x16x32_bf16(af[i], bfr[j], acc[i][j], 0, 0, 0);
    __syncthreads();
  }
  int cr = (lane >> 4) * 4, cc = lane & 15;
#pragma unroll
  for (int i = 0; i < 2; i++) {
    int lrow0 = wm * 32 + i * 16 + cr;
#pragma unroll
    for (int j = 0; j < 4; j++) {
      int ncol = n0 + wn * 64 + j * 16 + cc;
#pragma unroll
      for (int r = 0; r < 4; r++) {
        int lrow = lrow0 + r;
        int tk = ltok[lrow];
        if (tk >= 0)
          atomicAdd(out0 + (size_t)tk * Hn + ncol, lwv[lrow] * acc[i][j][r]);
      }
    }
  }
}

// ---------------- launch ----------------
extern "C" void kernel_launch(void* const* d_in, const int* in_sizes, int n_in,
                              void* d_out, int out_size, void* d_ws, size_t ws_size,
                              hipStream_t stream) {
  (void)in_sizes; (void)n_in; (void)out_size; (void)ws_size;
  const float* x      = (const float*)d_in[0];
  const float* freq   = (const float*)d_in[1];
  const float* n1w    = (const float*)d_in[2];
  const float* n2w    = (const float*)d_in[3];
  const float* wq     = (const float*)d_in[4];
  const float* wk     = (const float*)d_in[5];
  const float* wvp    = (const float*)d_in[6];
  const float* wo     = (const float*)d_in[7];
  const float* qn_w   = (const float*)d_in[8];
  const float* kn_w   = (const float*)d_in[9];
  const float* gate_w = (const float*)d_in[10];
  const float* w1     = (const float*)d_in[11];
  const float* w2     = (const float*)d_in[12];
  const float* w3     = (const float*)d_in[13];

  float* out0  = (float*)d_out;
  float* k_out = out0 + (size_t)Tn * Hn;
  float* v_out = k_out + (size_t)Tn * HKVn * HDn;

  char* wsb = (char*)d_ws;
  unsigned short* w13t = (unsigned short*)(wsb + 0);            // 64 MB
  unsigned short* w2t  = (unsigned short*)(wsb + 67108864);     // 32 MB
  unsigned short* tbf  = (unsigned short*)(wsb + 100663296);    // 4 MB
  unsigned short* tg   = (unsigned short*)(wsb + 104857600);    // 8 MB
  // act region (16 MB @113,246,208): used late (after k_moe13). Early-phase overlay:
  // projection-weight hi/lo copies (10 MB), dead before k_act writes.
  unsigned short* wqkvt_h = (unsigned short*)(wsb + 113246208); // 3 MB  [1536][1024]
  unsigned short* wqkvt_l = (unsigned short*)(wsb + 116391936); // 3 MB
  unsigned short* wot_h   = (unsigned short*)(wsb + 119537664); // 2 MB  [1024][1024]
  unsigned short* wot_l   = (unsigned short*)(wsb + 121634816); // 2 MB
  unsigned short* act  = (unsigned short*)(wsb + 113246208);    // 16 MB (late phase)
  // U overlay @130,023,424 (32 MB): f32/bf16 attention path, later reused as ug
  unsigned short* hnh  = (unsigned short*)(wsb + 130023424);    // 4 MB
  unsigned short* hnl  = (unsigned short*)(wsb + 134217728);    // 4 MB
  float* qkv_raw = (float*)(wsb + 138412032);                   // 12 MB [2048][1536]
  float* q_t   = (float*)(wsb + 150994944);                     // 8 MB
  unsigned short* kT8h = (unsigned short*)(wsb + 159383552);    // 1 MB
  unsigned short* kT8l = (unsigned short*)(wsb + 160432128);    // 1 MB
  unsigned short* vT8h = (unsigned short*)(wsb + 161480704);    // 1 MB
  unsigned short* vT8l = (unsigned short*)(wsb + 162529280);    // 1 MB
  unsigned short* ug = (unsigned short*)(wsb + 130023424);      // overlays the above
  unsigned short* yh = (unsigned short*)(wsb + 163577856);      // 4 MB (not overlaid)
  unsigned short* yl = (unsigned short*)(wsb + 167772160);      // 4 MB
  float* y2    = (float*)(wsb + 171966464);                     // 8 MB
  float* t_norm = (float*)(wsb + 150994944);                    // overlays q_t (dead)
  char*  rtr   = wsb + 180355072;
  int*   idxb   = (int*)(rtr);
  float* valb   = (float*)(rtr + 16384);
  int*   cnt    = (int*)(rtr + 32768);
  int*   offs   = (int*)(rtr + 32768 + 128);
  int*   cursor = (int*)(rtr + 32768 + 256);
  int*   tokl   = (int*)(rtr + 32768 + 384);
  float* wvl    = (float*)(rtr + 32768 + 384 + 16384);

  // MoE weight transposes (hi-only bf16, unchanged)
  k_tcvt<<<dim3(32, 16, 8), 256, 0, stream>>>(w1, w13t, 1024, 2048,
                                              (size_t)1024 * 2048, (size_t)4096 * 1024);
  k_tcvt<<<dim3(32, 16, 8), 256, 0, stream>>>(w3, w13t + (size_t)2048 * 1024, 1024, 2048,
                                              (size_t)1024 * 2048, (size_t)4096 * 1024);
  k_tcvt<<<dim3(16, 32, 8), 256, 0, stream>>>(w2, w2t, 2048, 1024,
                                              (size_t)2048 * 1024, (size_t)1024 * 2048);
  // projection weight transposes (hi/lo bf16): wqkvt[n][k], n = [q|k|v] concat
  k_tcvt2<<<dim3(16, 16), 256, 0, stream>>>(wq, wqkvt_h, wqkvt_l, 1024, 1024);
  k_tcvt2<<<dim3(4, 16), 256, 0, stream>>>(wk, wqkvt_h + (size_t)1024 * 1024,
                                           wqkvt_l + (size_t)1024 * 1024, 1024, 256);
  k_tcvt2<<<dim3(4, 16), 256, 0, stream>>>(wvp, wqkvt_h + (size_t)1280 * 1024,
                                           wqkvt_l + (size_t)1280 * 1024, 1024, 256);
  k_tcvt2<<<dim3(16, 16), 256, 0, stream>>>(wo, wot_h, wot_l, 1024, 1024);

  hipMemsetAsync(cnt, 0, 8 * sizeof(int), stream);

  k_rmsnorm<<<Tn, 256, 0, stream>>>(x, n1w, hnh, hnl);
  // fused qkv projection: [2048 x 1536] = hn @ [wq|wk|wv], split-precision MFMA
  k_pgemm<4><<<dim3(12, 16), 256, 0, stream>>>(hnh, hnl, wqkvt_h, wqkvt_l,
                                               qkv_raw, 1536, 1024);
  k_qkv_post<<<(Tn * 24) / 4, 256, 0, stream>>>(qkv_raw, qn_w, kn_w,
                                                freq, q_t, kT8h, kT8l, vT8h, vT8l,
                                                k_out, v_out);
  k_attn_mfma<<<Bn * HKVn * 64, 256, 0, stream>>>(q_t, kT8h, kT8l, vT8h, vT8l, yh, yl);
  // output projection: [2048 x 1024] = y @ wo, split-precision MFMA (64-row tiles)
  k_pgemm<2><<<dim3(8, 32), 256, 0, stream>>>(yh, yl, wot_h, wot_l, y2, 1024, 1024);
  k_resid_norm<<<Tn, 256, 0, stream>>>(x, y2, n2w, out0, t_norm, tbf);
  k_router<<<Tn / 4, 256, 0, stream>>>(t_norm, gate_w, idxb, valb, cnt);
  k_scan<<<1, 64, 0, stream>>>(cnt, offs, cursor);
  k_scatter<<<Tn / 256, 256, 0, stream>>>(idxb, valb, cursor, tokl, wvl);
  k_gather<<<2 * Tn, 256, 0, stream>>>(tbf, tokl, tg);
  k_moe13<<<dim3(16, 8, 8), 512, 0, stream>>>(tg, w13t, ug, cnt, offs);
  k_act<<<4096, 256, 0, stream>>>(ug, act);
  k_moe2<<<dim3(8, 16, 8), 512, 0, stream>>>(act, w2t, cnt, offs, tokl, wvl, out0);
}

// Round 5
// 669.059 us; speedup vs baseline: 1.0442x; 1.0156x over previous
//
#include <hip/hip_runtime.h>
#include <hip/hip_bf16.h>

#define HQn 16
#define HKVn 4
#define HDn 64
#define Bn 2
#define Sn 1024
#define Hn 1024
#define En 8
#define In 2048
#define Tn 2048
#define EPSf 1e-6f

typedef __attribute__((ext_vector_type(8))) short bf16x8;
typedef __attribute__((ext_vector_type(4))) float f32x4;

// ---------------- helpers ----------------
__device__ __forceinline__ unsigned short f2bf(float f) {
  unsigned u = __float_as_uint(f);
  u += 0x7fffu + ((u >> 16) & 1u);
  return (unsigned short)(u >> 16);
}
__device__ __forceinline__ float bf2f(unsigned short u) {
  return __uint_as_float(((unsigned)u) << 16);
}
__device__ __forceinline__ void gll16(const void* g, void* l) {
  __builtin_amdgcn_global_load_lds(
      (const __attribute__((address_space(1))) void*)g,
      (__attribute__((address_space(3))) void*)l, 16, 0, 0);
}
// counted vmcnt wait (T4). "memory" clobber fences LDS reads/writes across it.
template<int N> __device__ __forceinline__ void vmw() {
  if constexpr (N == 0) asm volatile("s_waitcnt vmcnt(0)" ::: "memory");
  else if constexpr (N == 4) asm volatile("s_waitcnt vmcnt(4)" ::: "memory");
  else if constexpr (N == 6) asm volatile("s_waitcnt vmcnt(6)" ::: "memory");
  else if constexpr (N == 8) asm volatile("s_waitcnt vmcnt(8)" ::: "memory");
}
#define BARRIER() __builtin_amdgcn_s_barrier()

// ---------------- transpose + f32->bf16: src[Z][R][C] -> dst[Z][C][R] ----------------
__global__ __launch_bounds__(256) void k_tcvt(
    const float* __restrict__ src, unsigned short* __restrict__ dst,
    int R, int C, size_t sZ, size_t dZ) {
  src += (size_t)blockIdx.z * sZ;
  dst += (size_t)blockIdx.z * dZ;
  int c0 = blockIdx.x * 64, r0 = blockIdx.y * 64;
  __shared__ float t[64][65];
  int tid = threadIdx.x;
  int lr = tid >> 4, lc = (tid & 15) * 4;
#pragma unroll
  for (int p = 0; p < 4; p++) {
    float4 v = *(const float4*)(src + (size_t)(r0 + lr + p * 16) * C + c0 + lc);
    t[lr + p * 16][lc + 0] = v.x; t[lr + p * 16][lc + 1] = v.y;
    t[lr + p * 16][lc + 2] = v.z; t[lr + p * 16][lc + 3] = v.w;
  }
  __syncthreads();
  int oc = tid >> 2;
  int seg = (tid & 3) * 16;
  unsigned pk[8];
#pragma unroll
  for (int j = 0; j < 8; j++) {
    unsigned short lo = f2bf(t[seg + 2 * j][oc]);
    unsigned short hi = f2bf(t[seg + 2 * j + 1][oc]);
    pk[j] = (unsigned)lo | ((unsigned)hi << 16);
  }
  uint4* dp = (uint4*)(dst + (size_t)(c0 + oc) * R + r0 + seg);
  dp[0] = make_uint4(pk[0], pk[1], pk[2], pk[3]);
  dp[1] = make_uint4(pk[4], pk[5], pk[6], pk[7]);
}

// ---------------- transpose + f32 -> (hi,lo) bf16: src[R][C] -> dsth/dstl[C][R] ------
__global__ __launch_bounds__(256) void k_tcvt2(
    const float* __restrict__ src, unsigned short* __restrict__ dsth,
    unsigned short* __restrict__ dstl, int R, int C) {
  int c0 = blockIdx.x * 64, r0 = blockIdx.y * 64;
  __shared__ float t[64][65];
  int tid = threadIdx.x;
  int lr = tid >> 4, lc = (tid & 15) * 4;
#pragma unroll
  for (int p = 0; p < 4; p++) {
    float4 v = *(const float4*)(src + (size_t)(r0 + lr + p * 16) * C + c0 + lc);
    t[lr + p * 16][lc + 0] = v.x; t[lr + p * 16][lc + 1] = v.y;
    t[lr + p * 16][lc + 2] = v.z; t[lr + p * 16][lc + 3] = v.w;
  }
  __syncthreads();
  int oc = tid >> 2;
  int seg = (tid & 3) * 16;
  unsigned pkh[8], pkl[8];
#pragma unroll
  for (int j = 0; j < 8; j++) {
    float a = t[seg + 2 * j][oc], b = t[seg + 2 * j + 1][oc];
    unsigned short ahh = f2bf(a), bhh = f2bf(b);
    unsigned short alo = f2bf(a - bf2f(ahh)), blo = f2bf(b - bf2f(bhh));
    pkh[j] = (unsigned)ahh | ((unsigned)bhh << 16);
    pkl[j] = (unsigned)alo | ((unsigned)blo << 16);
  }
  size_t db = (size_t)(c0 + oc) * R + r0 + seg;
  uint4* dph = (uint4*)(dsth + db);
  dph[0] = make_uint4(pkh[0], pkh[1], pkh[2], pkh[3]);
  dph[1] = make_uint4(pkh[4], pkh[5], pkh[6], pkh[7]);
  uint4* dpl = (uint4*)(dstl + db);
  dpl[0] = make_uint4(pkl[0], pkl[1], pkl[2], pkl[3]);
  dpl[1] = make_uint4(pkl[4], pkl[5], pkl[6], pkl[7]);
}

// ---------------- RMSNorm over H=1024, one block per row -> hi/lo bf16 ----------------
__global__ __launch_bounds__(256) void k_rmsnorm(
    const float* __restrict__ x, const float* __restrict__ w,
    unsigned short* __restrict__ outh, unsigned short* __restrict__ outl) {
  int row = blockIdx.x, tid = threadIdx.x;
  size_t off = (size_t)row * Hn + tid * 4;
  float4 v = *(const float4*)(x + off);
  float ss = v.x * v.x + v.y * v.y + v.z * v.z + v.w * v.w;
#pragma unroll
  for (int o = 32; o > 0; o >>= 1) ss += __shfl_xor(ss, o);
  __shared__ float ls[4];
  if ((tid & 63) == 0) ls[tid >> 6] = ss;
  __syncthreads();
  float tot = ls[0] + ls[1] + ls[2] + ls[3];
  float sc = rsqrtf(tot * (1.0f / Hn) + EPSf);
  float4 wv = *(const float4*)(w + tid * 4);
  float o0 = v.x * sc * wv.x, o1 = v.y * sc * wv.y;
  float o2 = v.z * sc * wv.z, o3 = v.w * sc * wv.w;
  ushort4 h4, l4;
  h4.x = f2bf(o0); l4.x = f2bf(o0 - bf2f(h4.x));
  h4.y = f2bf(o1); l4.y = f2bf(o1 - bf2f(h4.y));
  h4.z = f2bf(o2); l4.z = f2bf(o2 - bf2f(h4.z));
  h4.w = f2bf(o3); l4.w = f2bf(o3 - bf2f(h4.w));
  *(ushort4*)(outh + off) = h4;
  *(ushort4*)(outl + off) = l4;
}

// ---------------- residual add + RMSNorm (f32 outs + bf16 copy of t) ----------------
__global__ __launch_bounds__(256) void k_resid_norm(
    const float* __restrict__ x, const float* __restrict__ y,
    const float* __restrict__ w, float* __restrict__ x2out,
    float* __restrict__ tout, unsigned short* __restrict__ tbf) {
  int row = blockIdx.x, tid = threadIdx.x;
  size_t off = (size_t)row * Hn + tid * 4;
  float4 xv = *(const float4*)(x + off);
  float4 yv = *(const float4*)(y + off);
  float4 s;
  s.x = xv.x + yv.x; s.y = xv.y + yv.y; s.z = xv.z + yv.z; s.w = xv.w + yv.w;
  *(float4*)(x2out + off) = s;
  float ss = s.x * s.x + s.y * s.y + s.z * s.z + s.w * s.w;
#pragma unroll
  for (int o = 32; o > 0; o >>= 1) ss += __shfl_xor(ss, o);
  __shared__ float ls[4];
  if ((tid & 63) == 0) ls[tid >> 6] = ss;
  __syncthreads();
  float tot = ls[0] + ls[1] + ls[2] + ls[3];
  float sc = rsqrtf(tot * (1.0f / Hn) + EPSf);
  float4 wv4 = *(const float4*)(w + tid * 4);
  float4 t4;
  t4.x = s.x * sc * wv4.x; t4.y = s.y * sc * wv4.y;
  t4.z = s.z * sc * wv4.z; t4.w = s.w * sc * wv4.w;
  *(float4*)(tout + off) = t4;
  ushort4 b4;
  b4.x = f2bf(t4.x); b4.y = f2bf(t4.y); b4.z = f2bf(t4.z); b4.w = f2bf(t4.w);
  *(ushort4*)(tbf + off) = b4;
}

// ---------------- split-precision MFMA GEMM: C(MxN f32) = A @ B^T -------------------
// A hi/lo bf16 [M][K]; B hi/lo bf16 [N][K]. Tile (MT*32)x128, BK=32, 4 waves 2x2.
// T4 schedule: static double buffer, raw s_barrier + COUNTED vmcnt (never 0 in
// steady state) so one STAGE batch stays in flight through each COMP phase.
template<int MT>
__global__ __launch_bounds__(256) void k_pgemm(
    const unsigned short* __restrict__ Ah, const unsigned short* __restrict__ Al,
    const unsigned short* __restrict__ Bth, const unsigned short* __restrict__ Btl,
    float* __restrict__ C, int N, int K) {
  constexpr int ASL = MT * 1024;          // (MT*32) rows x 32 k shorts
  constexpr int NLD = (MT == 4) ? 8 : 6;  // gll16 per STAGE per thread
  __shared__ __align__(16) short sAh0[ASL], sAh1[ASL], sAl0[ASL], sAl1[ASL];
  __shared__ __align__(16) short sBh0[4096], sBh1[4096], sBl0[4096], sBl1[4096];
  int tid = threadIdx.x, wave = tid >> 6, lane = tid & 63;
  int n0 = blockIdx.x * 128, m0 = blockIdx.y * MT * 32;
  int wm = wave >> 1, wn = wave & 1;
  int r0 = ((tid >> 6) << 4) | (tid & 15);
  int k0 = ((tid >> 4) & 3) * 8;
  int r1 = r0 + 64;
  const unsigned short* pAh = Ah + (size_t)(m0 + r0) * K + k0;
  const unsigned short* pAl = Al + (size_t)(m0 + r0) * K + k0;
  const unsigned short* pBh0 = Bth + (size_t)(n0 + r0) * K + k0;
  const unsigned short* pBl0 = Btl + (size_t)(n0 + r0) * K + k0;
  const unsigned short* pBh1 = Bth + (size_t)(n0 + r1) * K + k0;
  const unsigned short* pBl1 = Btl + (size_t)(n0 + r1) * K + k0;
  const unsigned short* pAh1 = pAh;
  const unsigned short* pAl1 = pAl;
  if constexpr (MT == 4) {
    pAh1 = Ah + (size_t)(m0 + r1) * K + k0;
    pAl1 = Al + (size_t)(m0 + r1) * K + k0;
  }
  size_t d0 = (size_t)tid * 8, d1 = (size_t)(256 + tid) * 8;
#define PG_STAGE(S, kb) do { \
    gll16(pAh + (kb), sAh##S + d0); \
    gll16(pAl + (kb), sAl##S + d0); \
    if constexpr (MT == 4) { \
      gll16(pAh1 + (kb), sAh##S + d1); \
      gll16(pAl1 + (kb), sAl##S + d1); \
    } \
    gll16(pBh0 + (kb), sBh##S + d0); \
    gll16(pBl0 + (kb), sBl##S + d0); \
    gll16(pBh1 + (kb), sBh##S + d1); \
    gll16(pBl1 + (kb), sBl##S + d1); \
  } while (0)
#define PG_COMP(S) do { \
    bf16x8 ah[MT], al[MT], bh[4], bl[4]; \
    _Pragma("unroll") \
    for (int i = 0; i < MT; i++) { \
      ah[i] = *(const bf16x8*)(sAh##S + ((wm * MT + i) * 64 + lane) * 8); \
      al[i] = *(const bf16x8*)(sAl##S + ((wm * MT + i) * 64 + lane) * 8); \
    } \
    _Pragma("unroll") \
    for (int j = 0; j < 4; j++) { \
      bh[j] = *(const bf16x8*)(sBh##S + ((wn * 4 + j) * 64 + lane) * 8); \
      bl[j] = *(const bf16x8*)(sBl##S + ((wn * 4 + j) * 64 + lane) * 8); \
    } \
    _Pragma("unroll") \
    for (int i = 0; i < MT; i++) \
      _Pragma("unroll") \
      for (int j = 0; j < 4; j++) { \
        acc[i][j] = __builtin_amdgcn_mfma_f32_16x16x32_bf16(ah[i], bh[j], acc[i][j], 0, 0, 0); \
        acc[i][j] = __builtin_amdgcn_mfma_f32_16x16x32_bf16(ah[i], bl[j], acc[i][j], 0, 0, 0); \
        acc[i][j] = __builtin_amdgcn_mfma_f32_16x16x32_bf16(al[i], bh[j], acc[i][j], 0, 0, 0); \
      } \
  } while (0)
  f32x4 zf = {0.f, 0.f, 0.f, 0.f};
  f32x4 acc[MT][4];
#pragma unroll
  for (int i = 0; i < MT; i++)
#pragma unroll
    for (int j = 0; j < 4; j++) acc[i][j] = zf;
  PG_STAGE(0, 0);
  PG_STAGE(1, 32);
  vmw<NLD>();
  BARRIER();
  for (int kb = 0; kb < K; kb += 64) {
    PG_COMP(0);
    BARRIER();
    if (kb + 64 < K) { PG_STAGE(0, kb + 64); vmw<NLD>(); } else { vmw<0>(); }
    BARRIER();
    PG_COMP(1);
    BARRIER();
    if (kb + 96 < K) { PG_STAGE(1, kb + 96); vmw<NLD>(); } else { vmw<0>(); }
    BARRIER();
  }
#undef PG_STAGE
#undef PG_COMP
  int cr = (lane >> 4) * 4, cc = lane & 15;
#pragma unroll
  for (int i = 0; i < MT; i++) {
    int row0 = m0 + (wm * MT + i) * 16 + cr;
#pragma unroll
    for (int j = 0; j < 4; j++) {
      int col = n0 + (wn * 4 + j) * 16 + cc;
#pragma unroll
      for (int r = 0; r < 4; r++)
        C[(size_t)(row0 + r) * N + col] = acc[i][j][r];
    }
  }
}

// ---------------- q/k head-RMSNorm + RoPE; emits q_t f32, K/V split-bf16 swizzled ----
// input qkv: [token][1536] = [q 0..1023 | k 1024..1279 | v 1280..1535]
__global__ __launch_bounds__(256) void k_qkv_post(
    const float* __restrict__ qkv, const float* __restrict__ qn_w,
    const float* __restrict__ kn_w, const float* __restrict__ freq,
    float* __restrict__ q_t,
    unsigned short* __restrict__ kT8h, unsigned short* __restrict__ kT8l,
    unsigned short* __restrict__ vT8h, unsigned short* __restrict__ vT8l,
    float* __restrict__ k_out, float* __restrict__ v_out) {
  int gw = blockIdx.x * 4 + (threadIdx.x >> 6);
  int lane = threadIdx.x & 63;
  int token = gw / 24;
  int hh = gw % 24;
  int b = token / Sn, s = token % Sn;
  if (hh >= 20) {  // v head
    int h = hh - 20;
    float v = qkv[(size_t)token * 1536 + 1280 + h * HDn + lane];
    unsigned short hi = f2bf(v);
    unsigned short lo = f2bf(v - bf2f(hi));
    size_t vb = (((size_t)(b * HKVn + h) * 128 + (s >> 3)) * 64 + lane) * 8 + (s & 7);
    vT8h[vb] = hi; vT8l[vb] = lo;
    v_out[(size_t)token * (HKVn * HDn) + h * HDn + lane] = v;
    return;
  }
  bool isq = hh < 16;
  int h = isq ? hh : hh - 16;
  float val = isq ? qkv[(size_t)token * 1536 + h * HDn + lane]
                  : qkv[(size_t)token * 1536 + 1024 + h * HDn + lane];
  float ss = val * val;
#pragma unroll
  for (int o = 32; o > 0; o >>= 1) ss += __shfl_xor(ss, o);
  float scn = rsqrtf(ss * (1.0f / HDn) + EPSf);
  float w = isq ? qn_w[lane] : kn_w[lane];
  float xn = val * scn * w;
  float f = freq[(size_t)s * (HDn / 2) + (lane & 31)];
  float c = cosf(f), sn = sinf(f);
  float partner = __shfl_xor(xn, 32);
  float out = (lane < 32) ? (xn * c - partner * sn) : (partner * sn + xn * c);
  if (isq) {
    q_t[(((size_t)(b * HQn + h)) * Sn + s) * HDn + lane] = out;
  } else {
    unsigned short hi = f2bf(out);
    unsigned short lo = f2bf(out - bf2f(hi));
    size_t kb = (((size_t)(b * HKVn + h) * 8 + (lane >> 3)) * Sn + s) * 8 + (lane & 7);
    kT8h[kb] = hi; kT8l[kb] = lo;
    k_out[(size_t)token * (HKVn * HDn) + h * HDn + lane] = out;
  }
}

// ---------------- MFMA flash attention, split-precision (hi/lo bf16 = ~f32 exact) ----
__global__ __launch_bounds__(256) void k_attn_mfma(
    const float* __restrict__ q_t,
    const unsigned short* __restrict__ kT8h, const unsigned short* __restrict__ kT8l,
    const unsigned short* __restrict__ vT8h, const unsigned short* __restrict__ vT8l,
    unsigned short* __restrict__ yh, unsigned short* __restrict__ yl) {
  __shared__ __align__(16) unsigned short klh[4096], kll[4096];  // [do][key][din]
  __shared__ __align__(16) unsigned short vth[4096], vtl[4096];  // [ko][d][kin]
  __shared__ __align__(16) unsigned short Ph[4][1152], Pl[4][1152];  // [w][row][72]
  int bid = blockIdx.x;
  int qt = 63 - (bid & 63);       // long blocks first
  int kvh = (bid >> 6) & 3;
  int b = bid >> 8;
  int tid = threadIdx.x, w = tid >> 6, lane = tid & 63;
  int h = kvh * 4 + w;
  int g = lane >> 4, li = lane & 15;
  const float* qrow = q_t + (((size_t)(b * HQn + h) * Sn) + qt * 16 + li) * HDn + g * 8;
  bf16x8 qh[2], ql[2];
#pragma unroll
  for (int kc = 0; kc < 2; kc++) {
    float v[8];
    *(float4*)(v) = *(const float4*)(qrow + kc * 32);
    *(float4*)(v + 4) = *(const float4*)(qrow + kc * 32 + 4);
#pragma unroll
    for (int j = 0; j < 8; j++) {
      unsigned short hi = f2bf(v[j]);
      qh[kc][j] = (short)hi;
      ql[kc][j] = (short)f2bf(v[j] - bf2f(hi));
    }
  }
  size_t bh = (size_t)(b * HKVn + kvh) * 65536;
  f32x4 acc[4];
  f32x4 zf = {0.f, 0.f, 0.f, 0.f};
#pragma unroll
  for (int nt = 0; nt < 4; nt++) acc[nt] = zf;
  float m_[4] = {-1e30f, -1e30f, -1e30f, -1e30f};
  float l_[4] = {0.f, 0.f, 0.f, 0.f};
  int rowb = qt * 16 + g * 4;
  int kmax = qt * 16 + 15;
  for (int kk = 0; kk <= kmax; kk += 64) {
    __syncthreads();
#pragma unroll
    for (int i = 0; i < 2; i++) {
      int idx = w * 2 + i;
      gll16(kT8h + bh + (size_t)idx * 8192 + (size_t)kk * 8 + lane * 8, &klh[idx * 512]);
      gll16(kT8l + bh + (size_t)idx * 8192 + (size_t)kk * 8 + lane * 8, &kll[idx * 512]);
      gll16(vT8h + bh + (size_t)(kk / 8 + idx) * 512 + lane * 8, &vth[idx * 512]);
      gll16(vT8l + bh + (size_t)(kk / 8 + idx) * 512 + lane * 8, &vtl[idx * 512]);
    }
    __syncthreads();
    // ---- scores: 4 key-tiles of 16 ----
    f32x4 st[4];
#pragma unroll
    for (int kt = 0; kt < 4; kt++) st[kt] = zf;
#pragma unroll
    for (int kt = 0; kt < 4; kt++)
#pragma unroll
      for (int kc = 0; kc < 2; kc++) {
        int ko = (kc * 4 + g) * 512 + (kt * 16 + li) * 8;
        bf16x8 kh = *(const bf16x8*)&klh[ko];
        bf16x8 klo = *(const bf16x8*)&kll[ko];
        st[kt] = __builtin_amdgcn_mfma_f32_16x16x32_bf16(qh[kc], kh, st[kt], 0, 0, 0);
        st[kt] = __builtin_amdgcn_mfma_f32_16x16x32_bf16(qh[kc], klo, st[kt], 0, 0, 0);
        st[kt] = __builtin_amdgcn_mfma_f32_16x16x32_bf16(ql[kc], kh, st[kt], 0, 0, 0);
      }
    // ---- online softmax (rows rowb..rowb+3 per lane) ----
    float mx[4] = {-1e30f, -1e30f, -1e30f, -1e30f};
#pragma unroll
    for (int kt = 0; kt < 4; kt++) {
      int key = kk + kt * 16 + li;
#pragma unroll
      for (int r = 0; r < 4; r++) {
        float s = st[kt][r] * 0.125f;
        if (key > rowb + r) s = -1e30f;
        st[kt][r] = s;
        mx[r] = fmaxf(mx[r], s);
      }
    }
#pragma unroll
    for (int r = 0; r < 4; r++) {
#pragma unroll
      for (int o = 1; o < 16; o <<= 1) mx[r] = fmaxf(mx[r], __shfl_xor(mx[r], o));
      float mn = fmaxf(m_[r], mx[r]);
      mx[r] = __expf(m_[r] - mn);  // alpha
      m_[r] = mn;
    }
    float rs[4] = {0.f, 0.f, 0.f, 0.f};
#pragma unroll
    for (int kt = 0; kt < 4; kt++)
#pragma unroll
      for (int r = 0; r < 4; r++) {
        float p = __expf(st[kt][r] - m_[r]);
        rs[r] += p;
        unsigned short phh = f2bf(p);
        Ph[w][(g * 4 + r) * 72 + kt * 16 + li] = phh;
        Pl[w][(g * 4 + r) * 72 + kt * 16 + li] = f2bf(p - bf2f(phh));
      }
#pragma unroll
    for (int r = 0; r < 4; r++) {
#pragma unroll
      for (int o = 1; o < 16; o <<= 1) rs[r] += __shfl_xor(rs[r], o);
      l_[r] = l_[r] * mx[r] + rs[r];
#pragma unroll
      for (int nt = 0; nt < 4; nt++) acc[nt][r] *= mx[r];
    }
    // ---- PV ----
    bf16x8 pfh[2], pfl[2];
#pragma unroll
    for (int kc = 0; kc < 2; kc++) {
      int po = li * 72 + kc * 32 + g * 8;
      pfh[kc] = *(const bf16x8*)&Ph[w][po];
      pfl[kc] = *(const bf16x8*)&Pl[w][po];
    }
#pragma unroll
    for (int nt = 0; nt < 4; nt++)
#pragma unroll
      for (int kc = 0; kc < 2; kc++) {
        int vo = (kc * 4 + g) * 512 + (nt * 16 + li) * 8;
        bf16x8 vh = *(const bf16x8*)&vth[vo];
        bf16x8 vl = *(const bf16x8*)&vtl[vo];
        acc[nt] = __builtin_amdgcn_mfma_f32_16x16x32_bf16(pfh[kc], vh, acc[nt], 0, 0, 0);
        acc[nt] = __builtin_amdgcn_mfma_f32_16x16x32_bf16(pfh[kc], vl, acc[nt], 0, 0, 0);
        acc[nt] = __builtin_amdgcn_mfma_f32_16x16x32_bf16(pfl[kc], vh, acc[nt], 0, 0, 0);
      }
  }
  size_t ybase = ((size_t)(b * Sn) + qt * 16) * (HQn * HDn) + h * HDn;
#pragma unroll
  for (int r = 0; r < 4; r++) {
    float inv = 1.f / l_[r];
#pragma unroll
    for (int nt = 0; nt < 4; nt++) {
      size_t idx = ybase + (size_t)(g * 4 + r) * (HQn * HDn) + nt * 16 + li;
      float v = acc[nt][r] * inv;
      unsigned short hi = f2bf(v);
      yh[idx] = hi;
      yl[idx] = f2bf(v - bf2f(hi));
    }
  }
}

// ---------------- MoE router: softmax top-2, one wave per token (f32) ----------------
__global__ __launch_bounds__(256) void k_router(
    const float* __restrict__ t, const float* __restrict__ gw_,
    int* __restrict__ idx, float* __restrict__ val, int* __restrict__ cnt) {
  int tok = blockIdx.x * 4 + (threadIdx.x >> 6);
  int lane = threadIdx.x & 63;
  const float* tr = t + (size_t)tok * Hn;
  float s[8] = {0, 0, 0, 0, 0, 0, 0, 0};
  for (int hh = lane; hh < Hn; hh += 64) {
    float tv = tr[hh];
    float4 g0 = *(const float4*)(gw_ + hh * 8);
    float4 g1 = *(const float4*)(gw_ + hh * 8 + 4);
    s[0] = fmaf(tv, g0.x, s[0]); s[1] = fmaf(tv, g0.y, s[1]);
    s[2] = fmaf(tv, g0.z, s[2]); s[3] = fmaf(tv, g0.w, s[3]);
    s[4] = fmaf(tv, g1.x, s[4]); s[5] = fmaf(tv, g1.y, s[5]);
    s[6] = fmaf(tv, g1.z, s[6]); s[7] = fmaf(tv, g1.w, s[7]);
  }
#pragma unroll
  for (int e = 0; e < 8; e++)
#pragma unroll
    for (int off = 32; off > 0; off >>= 1) s[e] += __shfl_xor(s[e], off);
  if (lane == 0) {
    float mx = s[0];
    for (int e = 1; e < 8; e++) mx = fmaxf(mx, s[e]);
    float p[8];
    for (int e = 0; e < 8; e++) p[e] = __expf(s[e] - mx);
    int e0 = 0;
    for (int e = 1; e < 8; e++) if (p[e] > p[e0]) e0 = e;
    int e1 = (e0 == 0) ? 1 : 0;
    for (int e = 0; e < 8; e++) if (e != e0 && p[e] > p[e1]) e1 = e;
    float v0 = p[e0], v1 = p[e1], inv = 1.f / (v0 + v1);
    idx[tok * 2] = e0; idx[tok * 2 + 1] = e1;
    val[tok * 2] = v0 * inv; val[tok * 2 + 1] = v1 * inv;
    atomicAdd(&cnt[e0], 1); atomicAdd(&cnt[e1], 1);
  }
}

__global__ void k_scan(const int* __restrict__ cnt, int* __restrict__ offs,
                       int* __restrict__ cursor) {
  if (threadIdx.x == 0) {
    int run = 0;
    for (int e = 0; e < En; e++) { offs[e] = run; cursor[e] = run; run += cnt[e]; }
  }
}

__global__ __launch_bounds__(256) void k_scatter(
    const int* __restrict__ idx, const float* __restrict__ val,
    int* __restrict__ cursor, int* __restrict__ tokl, float* __restrict__ wvl) {
  int t = blockIdx.x * 256 + threadIdx.x;
#pragma unroll
  for (int slot = 0; slot < 2; slot++) {
    int e = idx[t * 2 + slot];
    int pos = atomicAdd(&cursor[e], 1);
    tokl[pos] = t;
    wvl[pos] = val[t * 2 + slot];
  }
}

// ---------------- gather token rows (bf16) into routed order ----------------
__global__ __launch_bounds__(256) void k_gather(
    const unsigned short* __restrict__ tb, const int* __restrict__ tokl,
    unsigned short* __restrict__ tg) {
  int r = blockIdx.x;
  int tk = tokl[r];
  const ushort4* s = (const ushort4*)(tb + (size_t)tk * Hn);
  ushort4* d = (ushort4*)(tg + (size_t)r * Hn);
  d[threadIdx.x] = s[threadIdx.x];
}

// ---------------- MoE GEMM1 (MFMA): ug[r][0:4096] = tg[r] @ w13t[e]^T ----------------
// 256x256 tile, BK=64, 8 waves (2x4, wave-tile 128x64), static dbuf, 128 KB LDS.
// T4: raw s_barrier + counted vmcnt(8) keeps one STAGE (64 KB/CU) in flight
// through every COMP phase; vmcnt(0) only at the tail.
__global__ __launch_bounds__(512) void k_moe13(
    const unsigned short* __restrict__ tg, const unsigned short* __restrict__ w13t,
    unsigned short* __restrict__ ug, const int* __restrict__ cnt,
    const int* __restrict__ offs) {
  int e = blockIdx.z;
  int n_e = cnt[e];
  int mt = blockIdx.y;
  if (mt * 256 >= n_e) return;
  int base = offs[e];
  int n0 = blockIdx.x * 256;
  const unsigned short* A = tg + (size_t)(base + mt * 256) * Hn;
  const unsigned short* Bt = w13t + (size_t)e * (2 * In) * Hn + (size_t)n0 * Hn;
  __shared__ __align__(16) short sA0[16384], sA1[16384];
  __shared__ __align__(16) short sB0[16384], sB1[16384];
  int tid = threadIdx.x;
  int wave = tid >> 6, lane = tid & 63;
  int wm = wave >> 2, wn = wave & 3;
  int rowLo = ((tid >> 6) << 4) | (tid & 15);   // 0..127
  int kLo = ((tid >> 4) & 3) * 8;               // 0,8,16,24
  const unsigned short* a0 = A + (size_t)rowLo * Hn + kLo;
  const unsigned short* a1 = A + (size_t)(rowLo + 128) * Hn + kLo;
  const unsigned short* b0 = Bt + (size_t)rowLo * Hn + kLo;
  const unsigned short* b1 = Bt + (size_t)(rowLo + 128) * Hn + kLo;
  size_t d0 = (size_t)tid * 8;
#define M13_STAGE(S, kb) do { \
    gll16(a0 + (kb), sA##S + d0); \
    gll16(a1 + (kb), sA##S + 4096 + d0); \
    gll16(a0 + (kb) + 32, sA##S + 8192 + d0); \
    gll16(a1 + (kb) + 32, sA##S + 12288 + d0); \
    gll16(b0 + (kb), sB##S + d0); \
    gll16(b1 + (kb), sB##S + 4096 + d0); \
    gll16(b0 + (kb) + 32, sB##S + 8192 + d0); \
    gll16(b1 + (kb) + 32, sB##S + 12288 + d0); \
  } while (0)
#define M13_COMP(S) do { \
    _Pragma("unroll") \
    for (int kk = 0; kk < 2; kk++) { \
      bf16x8 af[8], bfr[4]; \
      _Pragma("unroll") \
      for (int i = 0; i < 8; i++) \
        af[i] = *(const bf16x8*)(sA##S + kk * 8192 + ((wm * 8 + i) * 64 + lane) * 8); \
      _Pragma("unroll") \
      for (int j = 0; j < 4; j++) \
        bfr[j] = *(const bf16x8*)(sB##S + kk * 8192 + ((wn * 4 + j) * 64 + lane) * 8); \
      _Pragma("unroll") \
      for (int i = 0; i < 8; i++) \
        _Pragma("unroll") \
        for (int j = 0; j < 4; j++) \
          acc[i][j] = __builtin_amdgcn_mfma_f32_16x16x32_bf16(af[i], bfr[j], acc[i][j], 0, 0, 0); \
    } \
  } while (0)
  f32x4 zf = {0.f, 0.f, 0.f, 0.f};
  f32x4 acc[8][4];
#pragma unroll
  for (int i = 0; i < 8; i++)
#pragma unroll
    for (int j = 0; j < 4; j++) acc[i][j] = zf;
  M13_STAGE(0, 0);
  M13_STAGE(1, 64);
  vmw<8>();
  BARRIER();
  for (int kb = 0; kb < Hn; kb += 128) {
    M13_COMP(0);
    BARRIER();
    if (kb + 128 < Hn) { M13_STAGE(0, kb + 128); vmw<8>(); } else { vmw<0>(); }
    BARRIER();
    M13_COMP(1);
    BARRIER();
    if (kb + 192 < Hn) { M13_STAGE(1, kb + 192); vmw<8>(); } else { vmw<0>(); }
    BARRIER();
  }
#undef M13_STAGE
#undef M13_COMP
  int cr = (lane >> 4) * 4, cc = lane & 15;
#pragma unroll
  for (int i = 0; i < 8; i++) {
    int lrow0 = wm * 128 + i * 16 + cr;
#pragma unroll
    for (int j = 0; j < 4; j++) {
      int ncol = n0 + wn * 64 + j * 16 + cc;
#pragma unroll
      for (int r = 0; r < 4; r++) {
        int rr = mt * 256 + lrow0 + r;
        if (rr < n_e)
          ug[(size_t)(base + rr) * (2 * In) + ncol] = f2bf(acc[i][j][r]);
      }
    }
  }
}

// ---------------- act = silu(u) * g ----------------
__global__ __launch_bounds__(256) void k_act(
    const unsigned short* __restrict__ ug, unsigned short* __restrict__ act) {
  size_t p = ((size_t)blockIdx.x * 256 + threadIdx.x) * 8;
  size_t r = p >> 11;
  int c = (int)(p & 2047);
  const ushort4* up = (const ushort4*)(ug + r * 4096 + c);
  const ushort4* gp = (const ushort4*)(ug + r * 4096 + 2048 + c);
  ushort4* ap = (ushort4*)(act + r * 2048 + c);
#pragma unroll
  for (int h = 0; h < 2; h++) {
    ushort4 uu = up[h], gg = gp[h];
    ushort4 oo;
    float u0 = bf2f(uu.x), u1 = bf2f(uu.y), u2 = bf2f(uu.z), u3 = bf2f(uu.w);
    oo.x = f2bf(u0 / (1.f + __expf(-u0)) * bf2f(gg.x));
    oo.y = f2bf(u1 / (1.f + __expf(-u1)) * bf2f(gg.y));
    oo.z = f2bf(u2 / (1.f + __expf(-u2)) * bf2f(gg.z));
    oo.w = f2bf(u3 / (1.f + __expf(-u3)) * bf2f(gg.w));
    ap[h] = oo;
  }
}

// ---------------- MoE GEMM2 (MFMA): out0 += gate * (act @ w2t[e]^T) ----------------
// 128x128 tile, BK=64, 8 waves (4x2, wave-tile 32x64), static dbuf + T4 counted vmcnt.
__global__ __launch_bounds__(512) void k_moe2(
    const unsigned short* __restrict__ act, const unsigned short* __restrict__ w2t,
    const int* __restrict__ cnt, const int* __restrict__ offs,
    const int* __restrict__ tokl, const float* __restrict__ wvl,
    float* __restrict__ out0) {
  int e = blockIdx.z;
  int n_e = cnt[e];
  int mt = blockIdx.y;
  if (mt * 128 >= n_e) return;
  int base = offs[e];
  __shared__ int ltok[128];
  __shared__ float lwv[128];
  int tid = threadIdx.x;
  if (tid < 128) {
    int rr = mt * 128 + tid;
    bool v = rr < n_e;
    ltok[tid] = v ? tokl[base + rr] : -1;
    lwv[tid] = v ? wvl[base + rr] : 0.f;
  }
  __syncthreads();  // full sync: ltok/lwv visible to all waves before raw barriers
  const unsigned short* A = act + (size_t)(base + mt * 128) * In;
  const unsigned short* Bt = w2t + (size_t)e * Hn * In;
  __shared__ __align__(16) short sA0[8192], sA1[8192];
  __shared__ __align__(16) short sB0[8192], sB1[8192];
  int wave = tid >> 6, lane = tid & 63;
  int n0 = blockIdx.x * 128;
  int wm = wave >> 1, wn = wave & 1;
  int r0s = ((tid >> 6) << 4) | (tid & 15);  // 0..127
  int k0s = ((tid >> 4) & 3) * 8;
  const unsigned short* a0 = A + (size_t)r0s * In + k0s;
  const unsigned short* b0 = Bt + (size_t)(n0 + r0s) * In + k0s;
  size_t d0 = (size_t)tid * 8;
#define M2_STAGE(S, kb) do { \
    gll16(a0 + (kb), sA##S + d0); \
    gll16(a0 + (kb) + 32, sA##S + 4096 + d0); \
    gll16(b0 + (kb), sB##S + d0); \
    gll16(b0 + (kb) + 32, sB##S + 4096 + d0); \
  } while (0)
#define M2_COMP(S) do { \
    _Pragma("unroll") \
    for (int kk = 0; kk < 2; kk++) { \
      bf16x8 af[2], bfr[4]; \
      _Pragma("unroll") \
      for (int i = 0; i < 2; i++) \
        af[i] = *(const bf16x8*)(sA##S + kk * 4096 + ((wm * 2 + i) * 64 + lane) * 8); \
      _Pragma("unroll") \
      for (int j = 0; j < 4; j++) \
        bfr[j] = *(const bf16x8*)(sB##S + kk * 4096 + ((wn * 4 + j) * 64 + lane) * 8); \
      _Pragma("unroll") \
      for (int i = 0; i < 2; i++) \
        _Pragma("unroll") \
        for (int j = 0; j < 4; j++) \
          acc[i][j] = __builtin_amdgcn_mfma_f32_16x16x32_bf16(af[i], bfr[j], acc[i][j], 0, 0, 0); \
    } \
  } while (0)
  f32x4 zf = {0.f, 0.f, 0.f, 0.f};
  f32x4 acc[2][4];
#pragma unroll
  for (int i = 0; i < 2; i++)
#pragma unroll
    for (int j = 0; j < 4; j++) acc[i][j] = zf;
  M2_STAGE(0, 0);
  M2_STAGE(1, 64);
  vmw<4>();
  BARRIER();
  for (int kb = 0; kb < In; kb += 128) {
    M2_COMP(0);
    BARRIER();
    if (kb + 128 < In) { M2_STAGE(0, kb + 128); vmw<4>(); } else { vmw<0>(); }
    BARRIER();
    M2_COMP(1);
    BARRIER();
    if (kb + 192 < In) { M2_STAGE(1, kb + 192); vmw<4>(); } else { vmw<0>(); }
    BARRIER();
  }
#undef M2_STAGE
#undef M2_COMP
  int cr = (lane >> 4) * 4, cc = lane & 15;
#pragma unroll
  for (int i = 0; i < 2; i++) {
    int lrow0 = wm * 32 + i * 16 + cr;
#pragma unroll
    for (int j = 0; j < 4; j++) {
      int ncol = n0 + wn * 64 + j * 16 + cc;
#pragma unroll
      for (int r = 0; r < 4; r++) {
        int lrow = lrow0 + r;
        int tk = ltok[lrow];
        if (tk >= 0)
          atomicAdd(out0 + (size_t)tk * Hn + ncol, lwv[lrow] * acc[i][j][r]);
      }
    }
  }
}

// ---------------- launch ----------------
extern "C" void kernel_launch(void* const* d_in, const int* in_sizes, int n_in,
                              void* d_out, int out_size, void* d_ws, size_t ws_size,
                              hipStream_t stream) {
  (void)in_sizes; (void)n_in; (void)out_size; (void)ws_size;
  const float* x      = (const float*)d_in[0];
  const float* freq   = (const float*)d_in[1];
  const float* n1w    = (const float*)d_in[2];
  const float* n2w    = (const float*)d_in[3];
  const float* wq     = (const float*)d_in[4];
  const float* wk     = (const float*)d_in[5];
  const float* wvp    = (const float*)d_in[6];
  const float* wo     = (const float*)d_in[7];
  const float* qn_w   = (const float*)d_in[8];
  const float* kn_w   = (const float*)d_in[9];
  const float* gate_w = (const float*)d_in[10];
  const float* w1     = (const float*)d_in[11];
  const float* w2     = (const float*)d_in[12];
  const float* w3     = (const float*)d_in[13];

  float* out0  = (float*)d_out;
  float* k_out = out0 + (size_t)Tn * Hn;
  float* v_out = k_out + (size_t)Tn * HKVn * HDn;

  char* wsb = (char*)d_ws;
  unsigned short* w13t = (unsigned short*)(wsb + 0);            // 64 MB
  unsigned short* w2t  = (unsigned short*)(wsb + 67108864);     // 32 MB
  unsigned short* tbf  = (unsigned short*)(wsb + 100663296);    // 4 MB
  unsigned short* tg   = (unsigned short*)(wsb + 104857600);    // 8 MB
  // act region (16 MB @113,246,208): used late (after k_moe13). Early-phase overlay:
  // projection-weight hi/lo copies (10 MB), dead before k_act writes.
  unsigned short* wqkvt_h = (unsigned short*)(wsb + 113246208); // 3 MB  [1536][1024]
  unsigned short* wqkvt_l = (unsigned short*)(wsb + 116391936); // 3 MB
  unsigned short* wot_h   = (unsigned short*)(wsb + 119537664); // 2 MB  [1024][1024]
  unsigned short* wot_l   = (unsigned short*)(wsb + 121634816); // 2 MB
  unsigned short* act  = (unsigned short*)(wsb + 113246208);    // 16 MB (late phase)
  // U overlay @130,023,424 (32 MB): f32/bf16 attention path, later reused as ug
  unsigned short* hnh  = (unsigned short*)(wsb + 130023424);    // 4 MB
  unsigned short* hnl  = (unsigned short*)(wsb + 134217728);    // 4 MB
  float* qkv_raw = (float*)(wsb + 138412032);                   // 12 MB [2048][1536]
  float* q_t   = (float*)(wsb + 150994944);                     // 8 MB
  unsigned short* kT8h = (unsigned short*)(wsb + 159383552);    // 1 MB
  unsigned short* kT8l = (unsigned short*)(wsb + 160432128);    // 1 MB
  unsigned short* vT8h = (unsigned short*)(wsb + 161480704);    // 1 MB
  unsigned short* vT8l = (unsigned short*)(wsb + 162529280);    // 1 MB
  unsigned short* ug = (unsigned short*)(wsb + 130023424);      // overlays the above
  unsigned short* yh = (unsigned short*)(wsb + 163577856);      // 4 MB (not overlaid)
  unsigned short* yl = (unsigned short*)(wsb + 167772160);      // 4 MB
  float* y2    = (float*)(wsb + 171966464);                     // 8 MB
  float* t_norm = (float*)(wsb + 150994944);                    // overlays q_t (dead)
  char*  rtr   = wsb + 180355072;
  int*   idxb   = (int*)(rtr);
  float* valb   = (float*)(rtr + 16384);
  int*   cnt    = (int*)(rtr + 32768);
  int*   offs   = (int*)(rtr + 32768 + 128);
  int*   cursor = (int*)(rtr + 32768 + 256);
  int*   tokl   = (int*)(rtr + 32768 + 384);
  float* wvl    = (float*)(rtr + 32768 + 384 + 16384);

  // MoE weight transposes (hi-only bf16, unchanged)
  k_tcvt<<<dim3(32, 16, 8), 256, 0, stream>>>(w1, w13t, 1024, 2048,
                                              (size_t)1024 * 2048, (size_t)4096 * 1024);
  k_tcvt<<<dim3(32, 16, 8), 256, 0, stream>>>(w3, w13t + (size_t)2048 * 1024, 1024, 2048,
                                              (size_t)1024 * 2048, (size_t)4096 * 1024);
  k_tcvt<<<dim3(16, 32, 8), 256, 0, stream>>>(w2, w2t, 2048, 1024,
                                              (size_t)2048 * 1024, (size_t)1024 * 2048);
  // projection weight transposes (hi/lo bf16): wqkvt[n][k], n = [q|k|v] concat
  k_tcvt2<<<dim3(16, 16), 256, 0, stream>>>(wq, wqkvt_h, wqkvt_l, 1024, 1024);
  k_tcvt2<<<dim3(4, 16), 256, 0, stream>>>(wk, wqkvt_h + (size_t)1024 * 1024,
                                           wqkvt_l + (size_t)1024 * 1024, 1024, 256);
  k_tcvt2<<<dim3(4, 16), 256, 0, stream>>>(wvp, wqkvt_h + (size_t)1280 * 1024,
                                           wqkvt_l + (size_t)1280 * 1024, 1024, 256);
  k_tcvt2<<<dim3(16, 16), 256, 0, stream>>>(wo, wot_h, wot_l, 1024, 1024);

  hipMemsetAsync(cnt, 0, 8 * sizeof(int), stream);

  k_rmsnorm<<<Tn, 256, 0, stream>>>(x, n1w, hnh, hnl);
  // fused qkv projection: [2048 x 1536] = hn @ [wq|wk|wv], split-precision MFMA
  k_pgemm<4><<<dim3(12, 16), 256, 0, stream>>>(hnh, hnl, wqkvt_h, wqkvt_l,
                                               qkv_raw, 1536, 1024);
  k_qkv_post<<<(Tn * 24) / 4, 256, 0, stream>>>(qkv_raw, qn_w, kn_w,
                                                freq, q_t, kT8h, kT8l, vT8h, vT8l,
                                                k_out, v_out);
  k_attn_mfma<<<Bn * HKVn * 64, 256, 0, stream>>>(q_t, kT8h, kT8l, vT8h, vT8l, yh, yl);
  // output projection: [2048 x 1024] = y @ wo, split-precision MFMA (64-row tiles)
  k_pgemm<2><<<dim3(8, 32), 256, 0, stream>>>(yh, yl, wot_h, wot_l, y2, 1024, 1024);
  k_resid_norm<<<Tn, 256, 0, stream>>>(x, y2, n2w, out0, t_norm, tbf);
  k_router<<<Tn / 4, 256, 0, stream>>>(t_norm, gate_w, idxb, valb, cnt);
  k_scan<<<1, 64, 0, stream>>>(cnt, offs, cursor);
  k_scatter<<<Tn / 256, 256, 0, stream>>>(idxb, valb, cursor, tokl, wvl);
  k_gather<<<2 * Tn, 256, 0, stream>>>(tbf, tokl, tg);
  k_moe13<<<dim3(16, 8, 8), 512, 0, stream>>>(tg, w13t, ug, cnt, offs);
  k_act<<<4096, 256, 0, stream>>>(ug, act);
  k_moe2<<<dim3(8, 16, 8), 512, 0, stream>>>(act, w2t, cnt, offs, tokl, wvl, out0);
}